// Round 3
// baseline (2132.662 us; speedup 1.0000x reference)
//
#include <hip/hip_runtime.h>
#include <hip/hip_bf16.h>
#include <cstdint>

#define BB 2
#define TT 2048
#define DD 1024
#define HH 16
#define DHH 64
#define DFF 4096
#define LL 4
#define MM (BB*TT)   // 4096 rows

typedef __attribute__((ext_vector_type(8))) short short8v;
typedef __attribute__((ext_vector_type(4))) short short4v;
typedef __attribute__((ext_vector_type(4))) float floatx4;

typedef __attribute__((address_space(3))) void lds_void;
typedef const __attribute__((address_space(1))) void glb_void;

__device__ __forceinline__ void gload_lds16(const void* g, void* l) {
  __builtin_amdgcn_global_load_lds((glb_void*)g, (lds_void*)l, 16, 0, 0);
}

__device__ __forceinline__ float bf2f(short s) {
  union { unsigned u; float f; } v; v.u = ((unsigned)(unsigned short)s) << 16; return v.f;
}
__device__ __forceinline__ short f2bf(float f) {
  union { float f; unsigned u; } v; v.f = f;
  unsigned r = (v.u + 0x7fffu + ((v.u >> 16) & 1u)) >> 16;
  return (short)r;
}

// ---------------- fp32 -> bf16 cast of one layer's 6 weight matrices into one buffer
// dst element layout: Wq[0,1M) Wk[1M,2M) Wv[2M,3M) Wo[3M,4M) f1[4M,8.4M) f2[8.4M,12.6M)
#define SEG (DD*DD)              // 1048576
#define WTOT (4*SEG + 2*DFF*DD)  // 12582912
__global__ __launch_bounds__(256) void cast_layer(
    const float* __restrict__ wq, const float* __restrict__ wk,
    const float* __restrict__ wv, const float* __restrict__ wo,
    const float* __restrict__ f1, const float* __restrict__ f2,
    short* __restrict__ dst)
{
  const int i = (blockIdx.x * 256 + threadIdx.x) * 4;
  const float* src; int off;
  if      (i <     SEG) { src = wq; off = i; }
  else if (i < 2 * SEG) { src = wk; off = i - SEG; }
  else if (i < 3 * SEG) { src = wv; off = i - 2 * SEG; }
  else if (i < 4 * SEG) { src = wo; off = i - 3 * SEG; }
  else if (i < 4 * SEG + DFF * DD) { src = f1; off = i - 4 * SEG; }
  else { src = f2; off = i - 4 * SEG - DFF * DD; }
  const float4 v = *(const float4*)(src + off);
  short4v o; o[0] = f2bf(v.x); o[1] = f2bf(v.y); o[2] = f2bf(v.z); o[3] = f2bf(v.w);
  *(short4v*)(dst + i) = o;
}

// ---------------- GEMM: C[M][N] = A[M][K] @ W[N][K]^T + bias(fp32), optional exact GELU
// m97 structure: 128x128 tile, 4 waves (2x2), BK=32, global_load_lds width 16.
template<int GELU>
__global__ __launch_bounds__(256) void gemm_bt(
    const short* __restrict__ A, const short* __restrict__ W,
    const float* __restrict__ bias, short* __restrict__ C,
    int M, int N, int K)
{
  __shared__ __align__(16) short As[128 * 32];
  __shared__ __align__(16) short Bs[128 * 32];
  const int t = threadIdx.x;
  const int lane = t & 63, wave = t >> 6;
  const int wr = wave >> 1, wc = wave & 1;
  const int l15 = lane & 15, lg = lane >> 4;
  const int bx = blockIdx.x, by = blockIdx.y;

  floatx4 zero = {0.f, 0.f, 0.f, 0.f};
  floatx4 acc[4][4];
#pragma unroll
  for (int m = 0; m < 4; ++m)
#pragma unroll
    for (int n = 0; n < 4; ++n) acc[m][n] = zero;

  const size_t abase = (size_t)by * 128 * K;
  const size_t wbase = (size_t)bx * 128 * K;

  for (int k0 = 0; k0 < K; k0 += 32) {
#pragma unroll
    for (int i = 0; i < 2; ++i) {
      const int slot = i * 256 + t;             // 0..511, 16B each
      const int row = slot >> 2, cb = slot & 3; // 4x16B per 32-elem row
      const short* ga = A + abase + (size_t)row * K + k0 + cb * 8;
      const short* gw = W + wbase + (size_t)row * K + k0 + cb * 8;
      const int ldsoff = (i * 256 + wave * 64) * 8; // shorts; dest = base + lane*16B
      gload_lds16(ga, As + ldsoff);
      gload_lds16(gw, Bs + ldsoff);
    }
    __syncthreads();
    short8v af[4], bf[4];
#pragma unroll
    for (int m = 0; m < 4; ++m)
      af[m] = *(const short8v*)&As[(wr * 64 + m * 16 + l15) * 32 + lg * 8];
#pragma unroll
    for (int n = 0; n < 4; ++n)
      bf[n] = *(const short8v*)&Bs[(wc * 64 + n * 16 + l15) * 32 + lg * 8];
#pragma unroll
    for (int m = 0; m < 4; ++m)
#pragma unroll
      for (int n = 0; n < 4; ++n)
        acc[m][n] = __builtin_amdgcn_mfma_f32_16x16x32_bf16(af[m], bf[n], acc[m][n], 0, 0, 0);
    __syncthreads();
  }

#pragma unroll
  for (int n = 0; n < 4; ++n) {
    const int col = bx * 128 + wc * 64 + n * 16 + l15;
    const float bv = bias[col];
#pragma unroll
    for (int m = 0; m < 4; ++m) {
      const int row0 = by * 128 + wr * 64 + m * 16 + lg * 4;
#pragma unroll
      for (int jj = 0; jj < 4; ++jj) {
        float v = acc[m][n][jj] + bv;
        if (GELU) v = 0.5f * v * (1.f + erff(v * 0.70710678118f));
        C[(size_t)(row0 + jj) * N + col] = f2bf(v);
      }
    }
  }
}

// ---------------- V transpose per (b,h): v[B][T][H*64] -> vt[B][H][64][T]
__global__ __launch_bounds__(256) void transpose_v(
    const short* __restrict__ v, short* __restrict__ vt)
{
  __shared__ short tile[64][65];
  const int tb = blockIdx.x, h = blockIdx.y, b = blockIdx.z;
  const int t = threadIdx.x;
  const int r = t >> 2, c4 = (t & 3) * 16;
  const short* src = v + ((size_t)(b * TT + tb * 64 + r)) * DD + h * 64 + c4;
#pragma unroll
  for (int i = 0; i < 16; ++i) tile[r][c4 + i] = src[i];
  __syncthreads();
  short* dst = vt + ((size_t)((b * HH + h) * 64 + r)) * TT + tb * 64 + c4;
#pragma unroll
  for (int i = 0; i < 16; ++i) dst[i] = tile[c4 + i][r];
}

// ---------------- flash attention: 1 block = 64 q-rows of one (b,h); 4 waves x 16 rows
__global__ __launch_bounds__(256) void flash_attn(
    const short* __restrict__ q, const short* __restrict__ k,
    const short* __restrict__ vt, const int* __restrict__ mask,
    short* __restrict__ ctx)
{
  const int qb = blockIdx.x, h = blockIdx.y, b = blockIdx.z;
  const int t = threadIdx.x;
  const int lane = t & 63, wave = t >> 6;
  const int l15 = lane & 15, lg = lane >> 4;

  __shared__ __align__(16) short p_lds[4][16][72];
  short* prow = &p_lds[wave][0][0];

  const size_t qoff = ((size_t)(b * TT + qb * 64 + wave * 16 + l15)) * DD + h * 64;
  const short8v qf0 = *(const short8v*)(q + qoff + lg * 8);
  const short8v qf1 = *(const short8v*)(q + qoff + 32 + lg * 8);

  float m_run[4], l_run[4];
  floatx4 zero = {0.f, 0.f, 0.f, 0.f};
  floatx4 o[4];
#pragma unroll
  for (int jj = 0; jj < 4; ++jj) { m_run[jj] = -3e30f; l_run[jj] = 0.f; }
#pragma unroll
  for (int n = 0; n < 4; ++n) o[n] = zero;

  const short* vtb = vt + ((size_t)(b * HH + h)) * 64 * TT;

  for (int kb = 0; kb < TT / 64; ++kb) {
    // S = (Q K^T) for 16 q-rows x 64 keys per wave
    floatx4 s[4];
#pragma unroll
    for (int n = 0; n < 4; ++n) {
      const short* kp = k + ((size_t)(b * TT + kb * 64 + n * 16 + l15)) * DD + h * 64 + lg * 8;
      const short8v kf0 = *(const short8v*)kp;
      const short8v kf1 = *(const short8v*)(kp + 32);
      floatx4 a = zero;
      a = __builtin_amdgcn_mfma_f32_16x16x32_bf16(qf0, kf0, a, 0, 0, 0);
      a = __builtin_amdgcn_mfma_f32_16x16x32_bf16(qf1, kf1, a, 0, 0, 0);
      s[n] = a;
    }
    // scale + mask (col = key)
#pragma unroll
    for (int n = 0; n < 4; ++n) {
      const float cm = mask[b * TT + kb * 64 + n * 16 + l15] ? 0.f : -1e30f;
#pragma unroll
      for (int jj = 0; jj < 4; ++jj) s[n][jj] = s[n][jj] * 0.125f + cm;
    }
    // online softmax, row = lg*4+jj; reduce across the 16 l15-lanes
    float al[4];
#pragma unroll
    for (int jj = 0; jj < 4; ++jj) {
      float mx = fmaxf(fmaxf(s[0][jj], s[1][jj]), fmaxf(s[2][jj], s[3][jj]));
#pragma unroll
      for (int off = 8; off >= 1; off >>= 1) mx = fmaxf(mx, __shfl_xor(mx, off, 64));
      const float mnew = fmaxf(m_run[jj], mx);
      al[jj] = __expf(m_run[jj] - mnew);
      float sum = 0.f;
#pragma unroll
      for (int n = 0; n < 4; ++n) {
        const float p = __expf(s[n][jj] - mnew);
        s[n][jj] = p;
        sum += p;
      }
#pragma unroll
      for (int off = 8; off >= 1; off >>= 1) sum += __shfl_xor(sum, off, 64);
      l_run[jj] = l_run[jj] * al[jj] + sum;
      m_run[jj] = mnew;
    }
#pragma unroll
    for (int n = 0; n < 4; ++n)
#pragma unroll
      for (int jj = 0; jj < 4; ++jj) o[n][jj] *= al[jj];
    // P -> LDS (row-major [16 q][64 key], stride 72) then read as A-frags
#pragma unroll
    for (int n = 0; n < 4; ++n)
#pragma unroll
      for (int jj = 0; jj < 4; ++jj)
        prow[(lg * 4 + jj) * 72 + n * 16 + l15] = f2bf(s[n][jj]);
    const short8v pf0 = *(const short8v*)&prow[l15 * 72 + lg * 8];
    const short8v pf1 = *(const short8v*)&prow[l15 * 72 + 32 + lg * 8];
    // O += P @ V  (B-operand from VT: row=dh, contiguous keys)
#pragma unroll
    for (int n = 0; n < 4; ++n) {
      const short* vp = vtb + (size_t)(n * 16 + l15) * TT + kb * 64 + lg * 8;
      const short8v vf0 = *(const short8v*)vp;
      const short8v vf1 = *(const short8v*)(vp + 32);
      o[n] = __builtin_amdgcn_mfma_f32_16x16x32_bf16(pf0, vf0, o[n], 0, 0, 0);
      o[n] = __builtin_amdgcn_mfma_f32_16x16x32_bf16(pf1, vf1, o[n], 0, 0, 0);
    }
  }
#pragma unroll
  for (int jj = 0; jj < 4; ++jj) {
    const float inv = 1.f / l_run[jj];
    const int row = qb * 64 + wave * 16 + lg * 4 + jj;
#pragma unroll
    for (int n = 0; n < 4; ++n)
      ctx[((size_t)(b * TT + row)) * DD + h * 64 + n * 16 + l15] = f2bf(o[n][jj] * inv);
  }
}

// ---------------- fused residual-add + LayerNorm; fp32 residual stream, fp32 g/b
// outf: optional fp32 output (residual stream or final d_out); outb: optional bf16 output
__global__ __launch_bounds__(256) void add_ln(
    const float* __restrict__ xres, const short* __restrict__ add,
    const float* __restrict__ g, const float* __restrict__ bb,
    float* __restrict__ outf, short* __restrict__ outb)
{
  const int row = blockIdx.x, t = threadIdx.x;
  const int lane = t & 63, wave = t >> 6;
  const float4 xv = *(const float4*)(xres + (size_t)row * DD + t * 4);
  float y[4] = { xv.x, xv.y, xv.z, xv.w };
  if (add) {
    const short4v av = *(const short4v*)(add + (size_t)row * DD + t * 4);
#pragma unroll
    for (int i = 0; i < 4; ++i) y[i] += bf2f(av[i]);
  }
  float s = y[0] + y[1] + y[2] + y[3];
  float ss = y[0]*y[0] + y[1]*y[1] + y[2]*y[2] + y[3]*y[3];
#pragma unroll
  for (int off = 32; off >= 1; off >>= 1) {
    s  += __shfl_xor(s, off, 64);
    ss += __shfl_xor(ss, off, 64);
  }
  __shared__ float red[2][4];
  if (lane == 0) { red[0][wave] = s; red[1][wave] = ss; }
  __syncthreads();
  s  = red[0][0] + red[0][1] + red[0][2] + red[0][3];
  ss = red[1][0] + red[1][1] + red[1][2] + red[1][3];
  const float mu = s * (1.f / DD);
  const float var = ss * (1.f / DD) - mu * mu;
  const float rs = rsqrtf(var + 1e-5f);
  const float4 gv = *(const float4*)(g + t * 4);
  const float4 bv = *(const float4*)(bb + t * 4);
  float o[4];
  o[0] = (y[0] - mu) * rs * gv.x + bv.x;
  o[1] = (y[1] - mu) * rs * gv.y + bv.y;
  o[2] = (y[2] - mu) * rs * gv.z + bv.z;
  o[3] = (y[3] - mu) * rs * gv.w + bv.w;
  if (outf) *(float4*)(outf + (size_t)row * DD + t * 4) = make_float4(o[0], o[1], o[2], o[3]);
  if (outb) {
    short4v ov;
#pragma unroll
    for (int i = 0; i < 4; ++i) ov[i] = f2bf(o[i]);
    *(short4v*)(outb + (size_t)row * DD + t * 4) = ov;
  }
}

// ---------------- x (fp32) -> xf (fp32 copy) + xb (bf16)
__global__ __launch_bounds__(256) void cast_in(
    const float* __restrict__ x, float* __restrict__ xf,
    short* __restrict__ xb)
{
  const int i = (blockIdx.x * 256 + threadIdx.x) * 4;
  const float4 v = *(const float4*)(x + i);
  *(float4*)(xf + i) = v;
  short4v o; o[0] = f2bf(v.x); o[1] = f2bf(v.y); o[2] = f2bf(v.z); o[3] = f2bf(v.w);
  *(short4v*)(xb + i) = o;
}

extern "C" void kernel_launch(void* const* d_in, const int* in_sizes, int n_in,
                              void* d_out, int out_size, void* d_ws, size_t ws_size,
                              hipStream_t stream) {
  const float* x   = (const float*)d_in[0];
  const int* mask  = (const int*)d_in[1];
  const float* Wq  = (const float*)d_in[2];
  const float* bq  = (const float*)d_in[3];
  const float* Wk  = (const float*)d_in[4];
  const float* bk  = (const float*)d_in[5];
  const float* Wv  = (const float*)d_in[6];
  const float* bv  = (const float*)d_in[7];
  const float* Wo  = (const float*)d_in[8];
  const float* bo  = (const float*)d_in[9];
  const float* f1w = (const float*)d_in[10];
  const float* f1b = (const float*)d_in[11];
  const float* f2w = (const float*)d_in[12];
  const float* f2b = (const float*)d_in[13];
  const float* l1g = (const float*)d_in[14];
  const float* l1b = (const float*)d_in[15];
  const float* l2g = (const float*)d_in[16];
  const float* l2b = (const float*)d_in[17];
  const float* lfg = (const float*)d_in[18];
  const float* lfb = (const float*)d_in[19];
  float* out = (float*)d_out;   // reference output dtype is float32

  char* ws = (char*)d_ws;
  const size_t MB = 1u << 20;
  float* xf  = (float*)(ws);              // 16 MB fp32 residual stream
  short* xb  = (short*)(ws + 16 * MB);    // 8 MB bf16 mirror of x
  short* qb_ = (short*)(ws + 24 * MB);    // 8 MB
  short* kb_ = (short*)(ws + 32 * MB);    // 8 MB
  short* vb_ = (short*)(ws + 40 * MB);    // 8 MB
  short* vt_ = (short*)(ws + 48 * MB);    // 8 MB V^T
  short* ctx = (short*)(ws + 56 * MB);    // 8 MB
  short* tmp = (short*)(ws + 64 * MB);    // 8 MB attn_out / ff_out
  short* wbuf= (short*)(ws + 72 * MB);    // 24 MB: layer weights (bf16)
  short* hb  = qb_;                       // 33.6 MB FFN hidden, aliases dead q/k/v/vt/ctx

  cast_in<<<(MM * DD) / (256 * 4), 256, 0, stream>>>(x, xf, xb);

  for (int l = 0; l < LL; ++l) {
    cast_layer<<<WTOT / (256 * 4), 256, 0, stream>>>(
        Wq + (size_t)l * SEG, Wk + (size_t)l * SEG, Wv + (size_t)l * SEG, Wo + (size_t)l * SEG,
        f1w + (size_t)l * DFF * DD, f2w + (size_t)l * DD * DFF, wbuf);
    const short* wq_b = wbuf;
    const short* wk_b = wbuf + SEG;
    const short* wv_b = wbuf + 2 * SEG;
    const short* wo_b = wbuf + 3 * SEG;
    const short* f1_b = wbuf + 4 * SEG;
    const short* f2_b = wbuf + 4 * SEG + DFF * DD;

    gemm_bt<0><<<dim3(DD / 128, MM / 128), 256, 0, stream>>>(xb, wq_b, bq + l * DD, qb_, MM, DD, DD);
    gemm_bt<0><<<dim3(DD / 128, MM / 128), 256, 0, stream>>>(xb, wk_b, bk + l * DD, kb_, MM, DD, DD);
    gemm_bt<0><<<dim3(DD / 128, MM / 128), 256, 0, stream>>>(xb, wv_b, bv + l * DD, vb_, MM, DD, DD);
    transpose_v<<<dim3(TT / 64, HH, BB), 256, 0, stream>>>(vb_, vt_);
    flash_attn<<<dim3(TT / 64, HH, BB), 256, 0, stream>>>(qb_, kb_, vt_, mask, ctx);
    gemm_bt<0><<<dim3(DD / 128, MM / 128), 256, 0, stream>>>(ctx, wo_b, bo + l * DD, tmp, MM, DD, DD);
    add_ln<<<MM, 256, 0, stream>>>(xf, tmp, l1g + l * DD, l1b + l * DD, xf, xb);
    gemm_bt<1><<<dim3(DFF / 128, MM / 128), 256, 0, stream>>>(xb, f1_b, f1b + l * DFF, hb, MM, DFF, DD);
    gemm_bt<0><<<dim3(DD / 128, MM / 128), 256, 0, stream>>>(hb, f2_b, f2b + l * DD, tmp, MM, DD, DFF);
    add_ln<<<MM, 256, 0, stream>>>(xf, tmp, l2g + l * DD, l2b + l * DD, xf, xb);
  }
  // final LayerNorm -> fp32 d_out
  add_ln<<<MM, 256, 0, stream>>>(xf, nullptr, lfg, lfb, out, nullptr);
}

// Round 4
// 1574.468 us; speedup vs baseline: 1.3545x; 1.3545x over previous
//
#include <hip/hip_runtime.h>
#include <hip/hip_bf16.h>
#include <cstdint>

#define BB 2
#define TT 2048
#define DD 1024
#define HH 16
#define DHH 64
#define DFF 4096
#define LL 4
#define MM (BB*TT)   // 4096 rows
#define NT (TT/64)   // 32 key tiles

typedef __attribute__((ext_vector_type(8))) short short8v;
typedef __attribute__((ext_vector_type(4))) short short4v;
typedef __attribute__((ext_vector_type(4))) float floatx4;

typedef __attribute__((address_space(3))) void lds_void;
typedef const __attribute__((address_space(1))) void glb_void;

__device__ __forceinline__ void gload_lds16(const void* g, void* l) {
  __builtin_amdgcn_global_load_lds((glb_void*)g, (lds_void*)l, 16, 0, 0);
}

__device__ __forceinline__ float bf2f(short s) {
  union { unsigned u; float f; } v; v.u = ((unsigned)(unsigned short)s) << 16; return v.f;
}
__device__ __forceinline__ short f2bf(float f) {
  union { float f; unsigned u; } v; v.f = f;
  unsigned r = (v.u + 0x7fffu + ((v.u >> 16) & 1u)) >> 16;
  return (short)r;
}

// ---------------- fp32 -> bf16 cast of one layer's 6 weight matrices into one buffer
// dst layout: Wq[0,1M) Wk[1M,2M) Wv[2M,3M) Wo[3M,4M) f1[4M,8.4M) f2[8.4M,12.6M)
// Wq|Wk|Wv contiguous => fused QKV weight [3072][1024]
#define SEG (DD*DD)              // 1048576
#define WTOT (4*SEG + 2*DFF*DD)  // 12582912
__global__ __launch_bounds__(256) void cast_layer(
    const float* __restrict__ wq, const float* __restrict__ wk,
    const float* __restrict__ wv, const float* __restrict__ wo,
    const float* __restrict__ f1, const float* __restrict__ f2,
    short* __restrict__ dst)
{
  const int i = (blockIdx.x * 256 + threadIdx.x) * 4;
  const float* src; int off;
  if      (i <     SEG) { src = wq; off = i; }
  else if (i < 2 * SEG) { src = wk; off = i - SEG; }
  else if (i < 3 * SEG) { src = wv; off = i - 2 * SEG; }
  else if (i < 4 * SEG) { src = wo; off = i - 3 * SEG; }
  else if (i < 4 * SEG + DFF * DD) { src = f1; off = i - 4 * SEG; }
  else { src = f2; off = i - 4 * SEG - DFF * DD; }
  const float4 v = *(const float4*)(src + off);
  short4v o; o[0] = f2bf(v.x); o[1] = f2bf(v.y); o[2] = f2bf(v.z); o[3] = f2bf(v.w);
  *(short4v*)(dst + i) = o;
}

__global__ __launch_bounds__(256) void concat_bias(
    const float* __restrict__ a, const float* __restrict__ b,
    const float* __restrict__ c, float* __restrict__ o)
{
  const int i = blockIdx.x * 256 + threadIdx.x;   // 0..3071
  o[i] = i < DD ? a[i] : (i < 2 * DD ? b[i - DD] : c[i - 2 * DD]);
}

// ---------------- GEMM: C[M][N] = A[M][K] @ W[N][K]^T + bias(fp32), optional exact GELU
template<int GELU>
__global__ __launch_bounds__(256) void gemm_bt(
    const short* __restrict__ A, const short* __restrict__ W,
    const float* __restrict__ bias, short* __restrict__ C,
    int M, int N, int K)
{
  __shared__ __align__(16) short As[128 * 32];
  __shared__ __align__(16) short Bs[128 * 32];
  const int t = threadIdx.x;
  const int lane = t & 63, wave = t >> 6;
  const int wr = wave >> 1, wc = wave & 1;
  const int l15 = lane & 15, lg = lane >> 4;
  const int bx = blockIdx.x, by = blockIdx.y;

  floatx4 zero = {0.f, 0.f, 0.f, 0.f};
  floatx4 acc[4][4];
#pragma unroll
  for (int m = 0; m < 4; ++m)
#pragma unroll
    for (int n = 0; n < 4; ++n) acc[m][n] = zero;

  const size_t abase = (size_t)by * 128 * K;
  const size_t wbase = (size_t)bx * 128 * K;

  for (int k0 = 0; k0 < K; k0 += 32) {
#pragma unroll
    for (int i = 0; i < 2; ++i) {
      const int slot = i * 256 + t;             // 0..511, 16B each
      const int row = slot >> 2, cb = slot & 3; // 4x16B per 32-elem row
      const short* ga = A + abase + (size_t)row * K + k0 + cb * 8;
      const short* gw = W + wbase + (size_t)row * K + k0 + cb * 8;
      const int ldsoff = (i * 256 + wave * 64) * 8;
      gload_lds16(ga, As + ldsoff);
      gload_lds16(gw, Bs + ldsoff);
    }
    __syncthreads();
    short8v af[4], bf[4];
#pragma unroll
    for (int m = 0; m < 4; ++m)
      af[m] = *(const short8v*)&As[(wr * 64 + m * 16 + l15) * 32 + lg * 8];
#pragma unroll
    for (int n = 0; n < 4; ++n)
      bf[n] = *(const short8v*)&Bs[(wc * 64 + n * 16 + l15) * 32 + lg * 8];
#pragma unroll
    for (int m = 0; m < 4; ++m)
#pragma unroll
      for (int n = 0; n < 4; ++n)
        acc[m][n] = __builtin_amdgcn_mfma_f32_16x16x32_bf16(af[m], bf[n], acc[m][n], 0, 0, 0);
    __syncthreads();
  }

#pragma unroll
  for (int n = 0; n < 4; ++n) {
    const int col = bx * 128 + wc * 64 + n * 16 + l15;
    const float bv = bias[col];
#pragma unroll
    for (int m = 0; m < 4; ++m) {
      const int row0 = by * 128 + wr * 64 + m * 16 + lg * 4;
#pragma unroll
      for (int jj = 0; jj < 4; ++jj) {
        float v = acc[m][n][jj] + bv;
        if (GELU) v = 0.5f * v * (1.f + erff(v * 0.70710678118f));
        C[(size_t)(row0 + jj) * N + col] = f2bf(v);
      }
    }
  }
}

// ---------------- V transpose per (b,h): qkv[.][2048 + h*64 + dh] -> vt[B][H][64][T]
__global__ __launch_bounds__(256) void transpose_v(
    const short* __restrict__ qkv, short* __restrict__ vt)
{
  __shared__ short tile[64][65];
  const int tb = blockIdx.x, h = blockIdx.y, b = blockIdx.z;
  const int t = threadIdx.x;
  const int r = t >> 2, c4 = (t & 3) * 16;
  const short* src = qkv + ((size_t)(b * TT + tb * 64 + r)) * 3072 + 2048 + h * 64 + c4;
#pragma unroll
  for (int i = 0; i < 16; ++i) tile[r][c4 + i] = src[i];
  __syncthreads();
  short* dst = vt + ((size_t)((b * HH + h) * 64 + r)) * TT + tb * 64 + c4;
#pragma unroll
  for (int i = 0; i < 16; ++i) dst[i] = tile[c4 + i][r];
}

// ---------------- flash attention: 1 block = 64 q-rows of one (b,h); 4 waves x 16 rows
// K and V^T tiles double-buffered in LDS (XOR chunk-swizzle, pre-swizzled global src).
__global__ __launch_bounds__(256) void flash_attn(
    const short* __restrict__ qkv, const short* __restrict__ vt,
    const int* __restrict__ mask, short* __restrict__ ctx)
{
  const int qb = blockIdx.x, h = blockIdx.y, b = blockIdx.z;
  const int t = threadIdx.x;
  const int lane = t & 63, wave = t >> 6;
  const int l15 = lane & 15, lg = lane >> 4;

  __shared__ __align__(16) short Ks[2][64 * 64];   // [key][dh], chunk-swizzled
  __shared__ __align__(16) short Vs[2][64 * 64];   // [dh][key], chunk-swizzled
  __shared__ __align__(16) short p_lds[4][16 * 72];
  short* prow = p_lds[wave];

  // Q fragments: rows qb*64 + wave*16 + l15, row stride 3072, col offset h*64
  const short* qp = qkv + ((size_t)(b * TT + qb * 64 + wave * 16 + l15)) * 3072 + h * 64;
  const short8v qf0 = *(const short8v*)(qp + lg * 8);
  const short8v qf1 = *(const short8v*)(qp + 32 + lg * 8);

  const short* kbase = qkv + (size_t)b * TT * 3072 + 1024 + h * 64; // + key*3072 + dh
  const short* vtb   = vt + ((size_t)(b * HH + h)) * 64 * TT;       // + dh*TT + key

  // staging geometry: 8 chunks/tile (1KB each), wave w stages chunks 2w, 2w+1
  const int srow = lane >> 3;                 // row within 8-row chunk
  const int scol = (lane & 7) ^ (srow & 7);   // pre-swizzled source 16B-chunk

  float m_run[4], l_run[4];
  floatx4 zero = {0.f, 0.f, 0.f, 0.f};
  floatx4 o[4];
#pragma unroll
  for (int jj = 0; jj < 4; ++jj) { m_run[jj] = -3e30f; l_run[jj] = 0.f; }
#pragma unroll
  for (int n = 0; n < 4; ++n) o[n] = zero;

#define STAGE_KV(bufi, kb_) do {                                             \
    _Pragma("unroll")                                                        \
    for (int i_ = 0; i_ < 2; ++i_) {                                         \
      const int c_ = wave * 2 + i_;                                          \
      const int r_ = c_ * 8 + srow;                                          \
      gload_lds16(kbase + (size_t)((kb_) * 64 + r_) * 3072 + scol * 8,       \
                  &Ks[bufi][c_ * 512]);                                      \
      gload_lds16(vtb + (size_t)r_ * TT + (kb_) * 64 + scol * 8,             \
                  &Vs[bufi][c_ * 512]);                                      \
    }                                                                        \
  } while (0)

  STAGE_KV(0, 0);
  __syncthreads();

  int buf = 0;
  for (int kb = 0; kb < NT; ++kb) {
    if (kb + 1 < NT) STAGE_KV(buf ^ 1, kb + 1);

    // ---- S = Q K^T (16 q x 64 keys per wave), K frags from swizzled LDS
    floatx4 s[4];
#pragma unroll
    for (int n = 0; n < 4; ++n) {
      const int row = n * 16 + l15;
      const int ch0 = lg ^ (row & 7);
      const int ch1 = (lg + 4) ^ (row & 7);
      const short8v kf0 = *(const short8v*)&Ks[buf][row * 64 + ch0 * 8];
      const short8v kf1 = *(const short8v*)&Ks[buf][row * 64 + ch1 * 8];
      floatx4 a = zero;
      a = __builtin_amdgcn_mfma_f32_16x16x32_bf16(qf0, kf0, a, 0, 0, 0);
      a = __builtin_amdgcn_mfma_f32_16x16x32_bf16(qf1, kf1, a, 0, 0, 0);
      s[n] = a;
    }
    // scale + mask (col = key)
#pragma unroll
    for (int n = 0; n < 4; ++n) {
      const float cm = mask[b * TT + kb * 64 + n * 16 + l15] ? 0.f : -1e30f;
#pragma unroll
      for (int jj = 0; jj < 4; ++jj) s[n][jj] = s[n][jj] * 0.125f + cm;
    }
    // online softmax, row = lg*4+jj; reduce across the 16 l15-lanes
    float al[4];
#pragma unroll
    for (int jj = 0; jj < 4; ++jj) {
      float mx = fmaxf(fmaxf(s[0][jj], s[1][jj]), fmaxf(s[2][jj], s[3][jj]));
#pragma unroll
      for (int off = 8; off >= 1; off >>= 1) mx = fmaxf(mx, __shfl_xor(mx, off, 64));
      const float mnew = fmaxf(m_run[jj], mx);
      al[jj] = __expf(m_run[jj] - mnew);
      float sum = 0.f;
#pragma unroll
      for (int n = 0; n < 4; ++n) {
        const float p = __expf(s[n][jj] - mnew);
        s[n][jj] = p;
        sum += p;
      }
#pragma unroll
      for (int off = 8; off >= 1; off >>= 1) sum += __shfl_xor(sum, off, 64);
      l_run[jj] = l_run[jj] * al[jj] + sum;
      m_run[jj] = mnew;
    }
#pragma unroll
    for (int n = 0; n < 4; ++n)
#pragma unroll
      for (int jj = 0; jj < 4; ++jj) o[n][jj] *= al[jj];
    // P -> LDS (row-major [16 q][64 key], stride 72) then read as A-frags
#pragma unroll
    for (int n = 0; n < 4; ++n)
#pragma unroll
      for (int jj = 0; jj < 4; ++jj)
        prow[(lg * 4 + jj) * 72 + n * 16 + l15] = f2bf(s[n][jj]);
    const short8v pf0 = *(const short8v*)&prow[l15 * 72 + lg * 8];
    const short8v pf1 = *(const short8v*)&prow[l15 * 72 + 32 + lg * 8];
    // ---- O += P @ V, V frags from swizzled LDS (row = dh, cols = keys)
#pragma unroll
    for (int n = 0; n < 4; ++n) {
      const int row = n * 16 + l15;
      const int ch0 = lg ^ (row & 7);
      const int ch1 = (lg + 4) ^ (row & 7);
      const short8v vf0 = *(const short8v*)&Vs[buf][row * 64 + ch0 * 8];
      const short8v vf1 = *(const short8v*)&Vs[buf][row * 64 + ch1 * 8];
      o[n] = __builtin_amdgcn_mfma_f32_16x16x32_bf16(pf0, vf0, o[n], 0, 0, 0);
      o[n] = __builtin_amdgcn_mfma_f32_16x16x32_bf16(pf1, vf1, o[n], 0, 0, 0);
    }
    __syncthreads();
    buf ^= 1;
  }
#undef STAGE_KV

#pragma unroll
  for (int jj = 0; jj < 4; ++jj) {
    const float inv = 1.f / l_run[jj];
    const int row = qb * 64 + wave * 16 + lg * 4 + jj;
#pragma unroll
    for (int n = 0; n < 4; ++n)
      ctx[((size_t)(b * TT + row)) * DD + h * 64 + n * 16 + l15] = f2bf(o[n][jj] * inv);
  }
}

// ---------------- fused residual-add + LayerNorm; fp32 residual stream, fp32 g/b
__global__ __launch_bounds__(256) void add_ln(
    const float* __restrict__ xres, const short* __restrict__ add,
    const float* __restrict__ g, const float* __restrict__ bb,
    float* __restrict__ outf, short* __restrict__ outb)
{
  const int row = blockIdx.x, t = threadIdx.x;
  const int lane = t & 63, wave = t >> 6;
  const float4 xv = *(const float4*)(xres + (size_t)row * DD + t * 4);
  float y[4] = { xv.x, xv.y, xv.z, xv.w };
  if (add) {
    const short4v av = *(const short4v*)(add + (size_t)row * DD + t * 4);
#pragma unroll
    for (int i = 0; i < 4; ++i) y[i] += bf2f(av[i]);
  }
  float s = y[0] + y[1] + y[2] + y[3];
  float ss = y[0]*y[0] + y[1]*y[1] + y[2]*y[2] + y[3]*y[3];
#pragma unroll
  for (int off = 32; off >= 1; off >>= 1) {
    s  += __shfl_xor(s, off, 64);
    ss += __shfl_xor(ss, off, 64);
  }
  __shared__ float red[2][4];
  if (lane == 0) { red[0][wave] = s; red[1][wave] = ss; }
  __syncthreads();
  s  = red[0][0] + red[0][1] + red[0][2] + red[0][3];
  ss = red[1][0] + red[1][1] + red[1][2] + red[1][3];
  const float mu = s * (1.f / DD);
  const float var = ss * (1.f / DD) - mu * mu;
  const float rs = rsqrtf(var + 1e-5f);
  const float4 gv = *(const float4*)(g + t * 4);
  const float4 bv = *(const float4*)(bb + t * 4);
  float o[4];
  o[0] = (y[0] - mu) * rs * gv.x + bv.x;
  o[1] = (y[1] - mu) * rs * gv.y + bv.y;
  o[2] = (y[2] - mu) * rs * gv.z + bv.z;
  o[3] = (y[3] - mu) * rs * gv.w + bv.w;
  if (outf) *(float4*)(outf + (size_t)row * DD + t * 4) = make_float4(o[0], o[1], o[2], o[3]);
  if (outb) {
    short4v ov;
#pragma unroll
    for (int i = 0; i < 4; ++i) ov[i] = f2bf(o[i]);
    *(short4v*)(outb + (size_t)row * DD + t * 4) = ov;
  }
}

// ---------------- x (fp32) -> xf (fp32 copy) + xb (bf16)
__global__ __launch_bounds__(256) void cast_in(
    const float* __restrict__ x, float* __restrict__ xf,
    short* __restrict__ xb)
{
  const int i = (blockIdx.x * 256 + threadIdx.x) * 4;
  const float4 v = *(const float4*)(x + i);
  *(float4*)(xf + i) = v;
  short4v o; o[0] = f2bf(v.x); o[1] = f2bf(v.y); o[2] = f2bf(v.z); o[3] = f2bf(v.w);
  *(short4v*)(xb + i) = o;
}

extern "C" void kernel_launch(void* const* d_in, const int* in_sizes, int n_in,
                              void* d_out, int out_size, void* d_ws, size_t ws_size,
                              hipStream_t stream) {
  const float* x   = (const float*)d_in[0];
  const int* mask  = (const int*)d_in[1];
  const float* Wq  = (const float*)d_in[2];
  const float* bq  = (const float*)d_in[3];
  const float* Wk  = (const float*)d_in[4];
  const float* bk  = (const float*)d_in[5];
  const float* Wv  = (const float*)d_in[6];
  const float* bv  = (const float*)d_in[7];
  const float* Wo  = (const float*)d_in[8];
  const float* bo  = (const float*)d_in[9];
  const float* f1w = (const float*)d_in[10];
  const float* f1b = (const float*)d_in[11];
  const float* f2w = (const float*)d_in[12];
  const float* f2b = (const float*)d_in[13];
  const float* l1g = (const float*)d_in[14];
  const float* l1b = (const float*)d_in[15];
  const float* l2g = (const float*)d_in[16];
  const float* l2b = (const float*)d_in[17];
  const float* lfg = (const float*)d_in[18];
  const float* lfb = (const float*)d_in[19];
  float* out = (float*)d_out;   // reference output dtype is float32

  char* ws = (char*)d_ws;
  const size_t MB = 1u << 20;
  float* xf   = (float*)(ws);              // 16 MB fp32 residual stream
  short* xb   = (short*)(ws + 16 * MB);    // 8 MB bf16 x
  short* qkv  = (short*)(ws + 24 * MB);    // 24 MB fused QKV [4096][3072]
  short* vt_  = (short*)(ws + 48 * MB);    // 8 MB V^T [B][H][64][T]
  short* ctx  = (short*)(ws + 56 * MB);    // 8 MB
  short* tmp  = (short*)(ws + 64 * MB);    // 8 MB attn_out / ff_out
  float* fbias= (float*)(ws + 64 * MB);    // 12 KB fused QKV bias (aliases tmp; dead by Wo GEMM)
  short* wbuf = (short*)(ws + 72 * MB);    // 24 MB layer weights (bf16)
  short* hb   = qkv;                       // 32 MB FFN hidden, aliases dead qkv/vt

  cast_in<<<(MM * DD) / (256 * 4), 256, 0, stream>>>(x, xf, xb);

  for (int l = 0; l < LL; ++l) {
    cast_layer<<<WTOT / (256 * 4), 256, 0, stream>>>(
        Wq + (size_t)l * SEG, Wk + (size_t)l * SEG, Wv + (size_t)l * SEG, Wo + (size_t)l * SEG,
        f1w + (size_t)l * DFF * DD, f2w + (size_t)l * DD * DFF, wbuf);
    concat_bias<<<12, 256, 0, stream>>>(bq + l * DD, bk + l * DD, bv + l * DD, fbias);
    const short* wqkv_b = wbuf;                       // [3072][1024]
    const short* wo_b   = wbuf + 3 * SEG;
    const short* f1_b   = wbuf + 4 * SEG;
    const short* f2_b   = wbuf + 4 * SEG + DFF * DD;

    gemm_bt<0><<<dim3(3072 / 128, MM / 128), 256, 0, stream>>>(xb, wqkv_b, fbias, qkv, MM, 3072, DD);
    transpose_v<<<dim3(TT / 64, HH, BB), 256, 0, stream>>>(qkv, vt_);
    flash_attn<<<dim3(TT / 64, HH, BB), 256, 0, stream>>>(qkv, vt_, mask, ctx);
    gemm_bt<0><<<dim3(DD / 128, MM / 128), 256, 0, stream>>>(ctx, wo_b, bo + l * DD, tmp, MM, DD, DD);
    add_ln<<<MM, 256, 0, stream>>>(xf, tmp, l1g + l * DD, l1b + l * DD, xf, xb);
    gemm_bt<1><<<dim3(DFF / 128, MM / 128), 256, 0, stream>>>(xb, f1_b, f1b + l * DFF, hb, MM, DFF, DD);
    gemm_bt<0><<<dim3(DD / 128, MM / 128), 256, 0, stream>>>(hb, f2_b, f2b + l * DD, tmp, MM, DD, DFF);
    add_ln<<<MM, 256, 0, stream>>>(xf, tmp, l2g + l * DD, l2b + l * DD, xf, xb);
  }
  add_ln<<<MM, 256, 0, stream>>>(xf, nullptr, lfg, lfb, out, nullptr);
}

// Round 5
// 1434.829 us; speedup vs baseline: 1.4864x; 1.0973x over previous
//
#include <hip/hip_runtime.h>
#include <hip/hip_bf16.h>
#include <cstdint>

#define BB 2
#define TT 2048
#define DD 1024
#define HH 16
#define DHH 64
#define DFF 4096
#define LL 4
#define MM (BB*TT)   // 4096 rows
#define NT (TT/64)   // 32 key tiles

typedef __attribute__((ext_vector_type(8))) short short8v;
typedef __attribute__((ext_vector_type(4))) short short4v;
typedef __attribute__((ext_vector_type(4))) float floatx4;

typedef __attribute__((address_space(3))) void lds_void;
typedef const __attribute__((address_space(1))) void glb_void;

__device__ __forceinline__ void gload_lds16(const void* g, void* l) {
  __builtin_amdgcn_global_load_lds((glb_void*)g, (lds_void*)l, 16, 0, 0);
}

__device__ __forceinline__ float bf2f(short s) {
  union { unsigned u; float f; } v; v.u = ((unsigned)(unsigned short)s) << 16; return v.f;
}
__device__ __forceinline__ short f2bf(float f) {
  union { float f; unsigned u; } v; v.f = f;
  unsigned r = (v.u + 0x7fffu + ((v.u >> 16) & 1u)) >> 16;
  return (short)r;
}

// ---------------- fp32 -> bf16 cast of one layer's 6 weight matrices into one buffer
#define SEG (DD*DD)              // 1048576
#define WTOT (4*SEG + 2*DFF*DD)  // 12582912
__global__ __launch_bounds__(256) void cast_layer(
    const float* __restrict__ wq, const float* __restrict__ wk,
    const float* __restrict__ wv, const float* __restrict__ wo,
    const float* __restrict__ f1, const float* __restrict__ f2,
    short* __restrict__ dst)
{
  const int i = (blockIdx.x * 256 + threadIdx.x) * 4;
  const float* src; int off;
  if      (i <     SEG) { src = wq; off = i; }
  else if (i < 2 * SEG) { src = wk; off = i - SEG; }
  else if (i < 3 * SEG) { src = wv; off = i - 2 * SEG; }
  else if (i < 4 * SEG) { src = wo; off = i - 3 * SEG; }
  else if (i < 4 * SEG + DFF * DD) { src = f1; off = i - 4 * SEG; }
  else { src = f2; off = i - 4 * SEG - DFF * DD; }
  const float4 v = *(const float4*)(src + off);
  short4v o; o[0] = f2bf(v.x); o[1] = f2bf(v.y); o[2] = f2bf(v.z); o[3] = f2bf(v.w);
  *(short4v*)(dst + i) = o;
}

__global__ __launch_bounds__(256) void concat_bias(
    const float* __restrict__ a, const float* __restrict__ b,
    const float* __restrict__ c, float* __restrict__ o)
{
  const int i = blockIdx.x * 256 + threadIdx.x;   // 0..3071
  o[i] = i < DD ? a[i] : (i < 2 * DD ? b[i - DD] : c[i - 2 * DD]);
}

// ---------------- GEMM: C[M][N] = A[M][K] @ W[N][K]^T + bias(fp32), optional exact GELU
template<int GELU>
__global__ __launch_bounds__(256) void gemm_bt(
    const short* __restrict__ A, const short* __restrict__ W,
    const float* __restrict__ bias, short* __restrict__ C,
    int M, int N, int K)
{
  __shared__ __align__(16) short As[128 * 32];
  __shared__ __align__(16) short Bs[128 * 32];
  const int t = threadIdx.x;
  const int lane = t & 63, wave = t >> 6;
  const int wr = wave >> 1, wc = wave & 1;
  const int l15 = lane & 15, lg = lane >> 4;
  const int bx = blockIdx.x, by = blockIdx.y;

  floatx4 zero = {0.f, 0.f, 0.f, 0.f};
  floatx4 acc[4][4];
#pragma unroll
  for (int m = 0; m < 4; ++m)
#pragma unroll
    for (int n = 0; n < 4; ++n) acc[m][n] = zero;

  const size_t abase = (size_t)by * 128 * K;
  const size_t wbase = (size_t)bx * 128 * K;

  for (int k0 = 0; k0 < K; k0 += 32) {
#pragma unroll
    for (int i = 0; i < 2; ++i) {
      const int slot = i * 256 + t;             // 0..511, 16B each
      const int row = slot >> 2, cb = slot & 3;
      const short* ga = A + abase + (size_t)row * K + k0 + cb * 8;
      const short* gw = W + wbase + (size_t)row * K + k0 + cb * 8;
      const int ldsoff = (i * 256 + wave * 64) * 8;
      gload_lds16(ga, As + ldsoff);
      gload_lds16(gw, Bs + ldsoff);
    }
    __syncthreads();
    short8v af[4], bf[4];
#pragma unroll
    for (int m = 0; m < 4; ++m)
      af[m] = *(const short8v*)&As[(wr * 64 + m * 16 + l15) * 32 + lg * 8];
#pragma unroll
    for (int n = 0; n < 4; ++n)
      bf[n] = *(const short8v*)&Bs[(wc * 64 + n * 16 + l15) * 32 + lg * 8];
#pragma unroll
    for (int m = 0; m < 4; ++m)
#pragma unroll
      for (int n = 0; n < 4; ++n)
        acc[m][n] = __builtin_amdgcn_mfma_f32_16x16x32_bf16(af[m], bf[n], acc[m][n], 0, 0, 0);
    __syncthreads();
  }

#pragma unroll
  for (int n = 0; n < 4; ++n) {
    const int col = bx * 128 + wc * 64 + n * 16 + l15;
    const float bv = bias[col];
#pragma unroll
    for (int m = 0; m < 4; ++m) {
      const int row0 = by * 128 + wr * 64 + m * 16 + lg * 4;
#pragma unroll
      for (int jj = 0; jj < 4; ++jj) {
        float v = acc[m][n][jj] + bv;
        if (GELU) v = 0.5f * v * (1.f + erff(v * 0.70710678118f));
        C[(size_t)(row0 + jj) * N + col] = f2bf(v);
      }
    }
  }
}

// ---------------- V transpose per (b,h): qkv[.][2048 + h*64 + dh] -> vt[B][H][64][T]
__global__ __launch_bounds__(256) void transpose_v(
    const short* __restrict__ qkv, short* __restrict__ vt)
{
  __shared__ short tile[64][65];
  const int tb = blockIdx.x, h = blockIdx.y, b = blockIdx.z;
  const int t = threadIdx.x;
  const int r = t >> 2, c4 = (t & 3) * 16;
  const short* src = qkv + ((size_t)(b * TT + tb * 64 + r)) * 3072 + 2048 + h * 64 + c4;
#pragma unroll
  for (int i = 0; i < 16; ++i) tile[r][c4 + i] = src[i];
  __syncthreads();
  short* dst = vt + ((size_t)((b * HH + h) * 64 + r)) * TT + tb * 64 + c4;
#pragma unroll
  for (int i = 0; i < 16; ++i) dst[i] = tile[c4 + i][r];
}

// ---------------- flash attention: 1 block = 128 q-rows of one (b,h); 4 waves,
// each wave: 2 q-sets of 16 rows. Swapped QK^T (lane = one q-row) for cheap softmax.
#define PSTR 80
__global__ __launch_bounds__(256) void flash_attn(
    const short* __restrict__ qkv, const short* __restrict__ vt,
    const int* __restrict__ mask, short* __restrict__ ctx)
{
  const int qb = blockIdx.x, h = blockIdx.y, b = blockIdx.z;
  const int t = threadIdx.x;
  const int lane = t & 63, wave = t >> 6;
  const int l15 = lane & 15, lg = lane >> 4;

  __shared__ __align__(16) short Ks[2][64 * 64];   // [key][dh], chunk-swizzled
  __shared__ __align__(16) short Vs[2][64 * 64];   // [dh][key], chunk-swizzled
  __shared__ __align__(16) short p_lds[4][16 * PSTR];
  short* prow = p_lds[wave];

  // Q fragments for 2 q-sets: rows qb*128 + set*64 + wave*16 + l15
  short8v qf0[2], qf1[2];
#pragma unroll
  for (int s_ = 0; s_ < 2; ++s_) {
    const short* qp = qkv + ((size_t)(b * TT + qb * 128 + s_ * 64 + wave * 16 + l15)) * 3072 + h * 64;
    qf0[s_] = *(const short8v*)(qp + lg * 8);
    qf1[s_] = *(const short8v*)(qp + 32 + lg * 8);
  }

  const short* kbase = qkv + (size_t)b * TT * 3072 + 1024 + h * 64; // + key*3072 + dh
  const short* vtb   = vt + ((size_t)(b * HH + h)) * 64 * TT;       // + dh*TT + key

  // staging geometry: 8 chunks/tile (1KB each), wave w stages chunks 2w, 2w+1
  const int srow = lane >> 3;                 // row within 8-row chunk
  const int scol = (lane & 7) ^ (srow & 7);   // pre-swizzled source 16B-chunk

  float m_run[2] = { -3e30f, -3e30f };
  float l_run[2] = { 0.f, 0.f };
  floatx4 zero = {0.f, 0.f, 0.f, 0.f};
  floatx4 o[2][4];
#pragma unroll
  for (int s_ = 0; s_ < 2; ++s_)
#pragma unroll
    for (int n = 0; n < 4; ++n) o[s_][n] = zero;

#define STAGE_KV(bufi, kb_) do {                                             \
    _Pragma("unroll")                                                        \
    for (int i_ = 0; i_ < 2; ++i_) {                                         \
      const int c_ = wave * 2 + i_;                                          \
      const int r_ = c_ * 8 + srow;                                          \
      gload_lds16(kbase + (size_t)((kb_) * 64 + r_) * 3072 + scol * 8,       \
                  &Ks[bufi][c_ * 512]);                                      \
      gload_lds16(vtb + (size_t)r_ * TT + (kb_) * 64 + scol * 8,             \
                  &Vs[bufi][c_ * 512]);                                      \
    }                                                                        \
  } while (0)

  STAGE_KV(0, 0);
  __syncthreads();

  int buf = 0;
  for (int kb = 0; kb < NT; ++kb) {
    if (kb + 1 < NT) STAGE_KV(buf ^ 1, kb + 1);

    // K/V fragments for this tile (shared by both q-sets)
    short8v kf0[4], kf1[4], vf0[4], vf1[4];
#pragma unroll
    for (int n = 0; n < 4; ++n) {
      const int row = n * 16 + l15;
      const int ch0 = lg ^ (row & 7);
      const int ch1 = (lg + 4) ^ (row & 7);
      kf0[n] = *(const short8v*)&Ks[buf][row * 64 + ch0 * 8];
      kf1[n] = *(const short8v*)&Ks[buf][row * 64 + ch1 * 8];
      vf0[n] = *(const short8v*)&Vs[buf][row * 64 + ch0 * 8];
      vf1[n] = *(const short8v*)&Vs[buf][row * 64 + ch1 * 8];
    }

    // mask multipliers for this tile: key = n*16 + lg*4 + jj
    float cm[4][4];
#pragma unroll
    for (int n = 0; n < 4; ++n) {
      const int4 mv = *(const int4*)&mask[b * TT + kb * 64 + n * 16 + lg * 4];
      cm[n][0] = mv.x ? 0.f : -1e30f; cm[n][1] = mv.y ? 0.f : -1e30f;
      cm[n][2] = mv.z ? 0.f : -1e30f; cm[n][3] = mv.w ? 0.f : -1e30f;
    }

#pragma unroll
    for (int s_ = 0; s_ < 2; ++s_) {
      // ---- S^T = K Q^T : lane holds q-row = l15, keys n*16 + lg*4 + jj
      floatx4 s[4];
#pragma unroll
      for (int n = 0; n < 4; ++n) {
        floatx4 a = zero;
        a = __builtin_amdgcn_mfma_f32_16x16x32_bf16(kf0[n], qf0[s_], a, 0, 0, 0);
        a = __builtin_amdgcn_mfma_f32_16x16x32_bf16(kf1[n], qf1[s_], a, 0, 0, 0);
        s[n] = a;
      }
#pragma unroll
      for (int n = 0; n < 4; ++n)
#pragma unroll
        for (int jj = 0; jj < 4; ++jj) s[n][jj] = fmaf(s[n][jj], 0.125f, cm[n][jj]);

      // ---- online softmax for q-row l15 (16 local keys + 2 shuffles)
      float mx = -3e30f;
#pragma unroll
      for (int n = 0; n < 4; ++n)
#pragma unroll
        for (int jj = 0; jj < 4; ++jj) mx = fmaxf(mx, s[n][jj]);
      mx = fmaxf(mx, __shfl_xor(mx, 16, 64));
      mx = fmaxf(mx, __shfl_xor(mx, 32, 64));
      const float mnew = fmaxf(m_run[s_], mx);
      const float al = __expf(m_run[s_] - mnew);
      float sum = 0.f;
#pragma unroll
      for (int n = 0; n < 4; ++n)
#pragma unroll
        for (int jj = 0; jj < 4; ++jj) {
          const float p = __expf(s[n][jj] - mnew);
          s[n][jj] = p;
          sum += p;
        }
      sum += __shfl_xor(sum, 16, 64);
      sum += __shfl_xor(sum, 32, 64);
      l_run[s_] = l_run[s_] * al + sum;
      m_run[s_] = mnew;

      // redistribute al from q=l15 layout to o layout (q = lg*4+jj)
      float alo[4];
#pragma unroll
      for (int jj = 0; jj < 4; ++jj) alo[jj] = __shfl(al, lg * 4 + jj, 16);
#pragma unroll
      for (int n = 0; n < 4; ++n)
#pragma unroll
        for (int jj = 0; jj < 4; ++jj) o[s_][n][jj] *= alo[jj];

      // ---- P -> LDS [q=l15][key], b64 writes; read back as A-frags (row=q)
#pragma unroll
      for (int n = 0; n < 4; ++n) {
        short4v pv;
#pragma unroll
        for (int jj = 0; jj < 4; ++jj) pv[jj] = f2bf(s[n][jj]);
        *(short4v*)&prow[l15 * PSTR + n * 16 + lg * 4] = pv;
      }
      const short8v pf0 = *(const short8v*)&prow[l15 * PSTR + lg * 8];
      const short8v pf1 = *(const short8v*)&prow[l15 * PSTR + 32 + lg * 8];

      // ---- O += P @ V
#pragma unroll
      for (int n = 0; n < 4; ++n) {
        o[s_][n] = __builtin_amdgcn_mfma_f32_16x16x32_bf16(pf0, vf0[n], o[s_][n], 0, 0, 0);
        o[s_][n] = __builtin_amdgcn_mfma_f32_16x16x32_bf16(pf1, vf1[n], o[s_][n], 0, 0, 0);
      }
    }
    __syncthreads();
    buf ^= 1;
  }
#undef STAGE_KV

#pragma unroll
  for (int s_ = 0; s_ < 2; ++s_)
#pragma unroll
    for (int jj = 0; jj < 4; ++jj) {
      const float inv = 1.f / __shfl(l_run[s_], lg * 4 + jj, 16);
      const int row = qb * 128 + s_ * 64 + wave * 16 + lg * 4 + jj;
#pragma unroll
      for (int n = 0; n < 4; ++n)
        ctx[((size_t)(b * TT + row)) * DD + h * 64 + n * 16 + l15] = f2bf(o[s_][n][jj] * inv);
    }
}

// ---------------- fused residual-add + LayerNorm; fp32 residual stream, fp32 g/b
__global__ __launch_bounds__(256) void add_ln(
    const float* __restrict__ xres, const short* __restrict__ add,
    const float* __restrict__ g, const float* __restrict__ bb,
    float* __restrict__ outf, short* __restrict__ outb)
{
  const int row = blockIdx.x, t = threadIdx.x;
  const int lane = t & 63, wave = t >> 6;
  const float4 xv = *(const float4*)(xres + (size_t)row * DD + t * 4);
  float y[4] = { xv.x, xv.y, xv.z, xv.w };
  if (add) {
    const short4v av = *(const short4v*)(add + (size_t)row * DD + t * 4);
#pragma unroll
    for (int i = 0; i < 4; ++i) y[i] += bf2f(av[i]);
  }
  float s = y[0] + y[1] + y[2] + y[3];
  float ss = y[0]*y[0] + y[1]*y[1] + y[2]*y[2] + y[3]*y[3];
#pragma unroll
  for (int off = 32; off >= 1; off >>= 1) {
    s  += __shfl_xor(s, off, 64);
    ss += __shfl_xor(ss, off, 64);
  }
  __shared__ float red[2][4];
  if (lane == 0) { red[0][wave] = s; red[1][wave] = ss; }
  __syncthreads();
  s  = red[0][0] + red[0][1] + red[0][2] + red[0][3];
  ss = red[1][0] + red[1][1] + red[1][2] + red[1][3];
  const float mu = s * (1.f / DD);
  const float var = ss * (1.f / DD) - mu * mu;
  const float rs = rsqrtf(var + 1e-5f);
  const float4 gv = *(const float4*)(g + t * 4);
  const float4 bv = *(const float4*)(bb + t * 4);
  float o[4];
  o[0] = (y[0] - mu) * rs * gv.x + bv.x;
  o[1] = (y[1] - mu) * rs * gv.y + bv.y;
  o[2] = (y[2] - mu) * rs * gv.z + bv.z;
  o[3] = (y[3] - mu) * rs * gv.w + bv.w;
  if (outf) *(float4*)(outf + (size_t)row * DD + t * 4) = make_float4(o[0], o[1], o[2], o[3]);
  if (outb) {
    short4v ov;
#pragma unroll
    for (int i = 0; i < 4; ++i) ov[i] = f2bf(o[i]);
    *(short4v*)(outb + (size_t)row * DD + t * 4) = ov;
  }
}

// ---------------- x (fp32) -> xf (fp32 copy) + xb (bf16)
__global__ __launch_bounds__(256) void cast_in(
    const float* __restrict__ x, float* __restrict__ xf,
    short* __restrict__ xb)
{
  const int i = (blockIdx.x * 256 + threadIdx.x) * 4;
  const float4 v = *(const float4*)(x + i);
  *(float4*)(xf + i) = v;
  short4v o; o[0] = f2bf(v.x); o[1] = f2bf(v.y); o[2] = f2bf(v.z); o[3] = f2bf(v.w);
  *(short4v*)(xb + i) = o;
}

extern "C" void kernel_launch(void* const* d_in, const int* in_sizes, int n_in,
                              void* d_out, int out_size, void* d_ws, size_t ws_size,
                              hipStream_t stream) {
  const float* x   = (const float*)d_in[0];
  const int* mask  = (const int*)d_in[1];
  const float* Wq  = (const float*)d_in[2];
  const float* bq  = (const float*)d_in[3];
  const float* Wk  = (const float*)d_in[4];
  const float* bk  = (const float*)d_in[5];
  const float* Wv  = (const float*)d_in[6];
  const float* bv  = (const float*)d_in[7];
  const float* Wo  = (const float*)d_in[8];
  const float* bo  = (const float*)d_in[9];
  const float* f1w = (const float*)d_in[10];
  const float* f1b = (const float*)d_in[11];
  const float* f2w = (const float*)d_in[12];
  const float* f2b = (const float*)d_in[13];
  const float* l1g = (const float*)d_in[14];
  const float* l1b = (const float*)d_in[15];
  const float* l2g = (const float*)d_in[16];
  const float* l2b = (const float*)d_in[17];
  const float* lfg = (const float*)d_in[18];
  const float* lfb = (const float*)d_in[19];
  float* out = (float*)d_out;   // reference output dtype is float32

  char* ws = (char*)d_ws;
  const size_t MB = 1u << 20;
  float* xf   = (float*)(ws);              // 16 MB fp32 residual stream
  short* xb   = (short*)(ws + 16 * MB);    // 8 MB bf16 x
  short* qkv  = (short*)(ws + 24 * MB);    // 24 MB fused QKV [4096][3072]
  short* vt_  = (short*)(ws + 48 * MB);    // 8 MB V^T [B][H][64][T]
  short* ctx  = (short*)(ws + 56 * MB);    // 8 MB
  short* tmp  = (short*)(ws + 64 * MB);    // 8 MB attn_out / ff_out
  float* fbias= (float*)(ws + 64 * MB);    // 12 KB fused QKV bias (aliases tmp; dead by Wo GEMM)
  short* wbuf = (short*)(ws + 72 * MB);    // 24 MB layer weights (bf16)
  short* hb   = qkv;                       // 32 MB FFN hidden, aliases dead qkv/vt

  cast_in<<<(MM * DD) / (256 * 4), 256, 0, stream>>>(x, xf, xb);

  for (int l = 0; l < LL; ++l) {
    cast_layer<<<WTOT / (256 * 4), 256, 0, stream>>>(
        Wq + (size_t)l * SEG, Wk + (size_t)l * SEG, Wv + (size_t)l * SEG, Wo + (size_t)l * SEG,
        f1w + (size_t)l * DFF * DD, f2w + (size_t)l * DD * DFF, wbuf);
    concat_bias<<<12, 256, 0, stream>>>(bq + l * DD, bk + l * DD, bv + l * DD, fbias);
    const short* wqkv_b = wbuf;                       // [3072][1024]
    const short* wo_b   = wbuf + 3 * SEG;
    const short* f1_b   = wbuf + 4 * SEG;
    const short* f2_b   = wbuf + 4 * SEG + DFF * DD;

    gemm_bt<0><<<dim3(3072 / 128, MM / 128), 256, 0, stream>>>(xb, wqkv_b, fbias, qkv, MM, 3072, DD);
    transpose_v<<<dim3(TT / 64, HH, BB), 256, 0, stream>>>(qkv, vt_);
    flash_attn<<<dim3(TT / 128, HH, BB), 256, 0, stream>>>(qkv, vt_, mask, ctx);
    gemm_bt<0><<<dim3(DD / 128, MM / 128), 256, 0, stream>>>(ctx, wo_b, bo + l * DD, tmp, MM, DD, DD);
    add_ln<<<MM, 256, 0, stream>>>(xf, tmp, l1g + l * DD, l1b + l * DD, xf, xb);
    gemm_bt<1><<<dim3(DFF / 128, MM / 128), 256, 0, stream>>>(xb, f1_b, f1b + l * DFF, hb, MM, DFF, DD);
    gemm_bt<0><<<dim3(DD / 128, MM / 128), 256, 0, stream>>>(hb, f2_b, f2b + l * DD, tmp, MM, DD, DFF);
    add_ln<<<MM, 256, 0, stream>>>(xf, tmp, l2g + l * DD, l2b + l * DD, xf, xb);
  }
  add_ln<<<MM, 256, 0, stream>>>(xf, nullptr, lfg, lfb, out, nullptr);
}

// Round 6
// 1246.765 us; speedup vs baseline: 1.7106x; 1.1508x over previous
//
#include <hip/hip_runtime.h>
#include <hip/hip_bf16.h>
#include <cstdint>

#define BB 2
#define TT 2048
#define DD 1024
#define HH 16
#define DHH 64
#define DFF 4096
#define LL 4
#define MM (BB*TT)   // 4096 rows
#define NT (TT/64)   // 32 key tiles

typedef __attribute__((ext_vector_type(8))) short short8v;
typedef __attribute__((ext_vector_type(4))) short short4v;
typedef __attribute__((ext_vector_type(4))) float floatx4;

typedef __attribute__((address_space(3))) void lds_void;
typedef const __attribute__((address_space(1))) void glb_void;

__device__ __forceinline__ void gload_lds16(const void* g, void* l) {
  __builtin_amdgcn_global_load_lds((glb_void*)g, (lds_void*)l, 16, 0, 0);
}

__device__ __forceinline__ float bf2f(short s) {
  union { unsigned u; float f; } v; v.u = ((unsigned)(unsigned short)s) << 16; return v.f;
}
__device__ __forceinline__ short f2bf(float f) {
  union { float f; unsigned u; } v; v.f = f;
  unsigned r = (v.u + 0x7fffu + ((v.u >> 16) & 1u)) >> 16;
  return (short)r;
}

// ---------------- fp32 -> bf16 cast of one layer's 6 weight matrices into one buffer
#define SEG (DD*DD)              // 1048576
#define WTOT (4*SEG + 2*DFF*DD)  // 12582912
__global__ __launch_bounds__(256) void cast_layer(
    const float* __restrict__ wq, const float* __restrict__ wk,
    const float* __restrict__ wv, const float* __restrict__ wo,
    const float* __restrict__ f1, const float* __restrict__ f2,
    short* __restrict__ dst)
{
  const int i = (blockIdx.x * 256 + threadIdx.x) * 4;
  const float* src; int off;
  if      (i <     SEG) { src = wq; off = i; }
  else if (i < 2 * SEG) { src = wk; off = i - SEG; }
  else if (i < 3 * SEG) { src = wv; off = i - 2 * SEG; }
  else if (i < 4 * SEG) { src = wo; off = i - 3 * SEG; }
  else if (i < 4 * SEG + DFF * DD) { src = f1; off = i - 4 * SEG; }
  else { src = f2; off = i - 4 * SEG - DFF * DD; }
  const float4 v = *(const float4*)(src + off);
  short4v o; o[0] = f2bf(v.x); o[1] = f2bf(v.y); o[2] = f2bf(v.z); o[3] = f2bf(v.w);
  *(short4v*)(dst + i) = o;
}

__global__ __launch_bounds__(256) void concat_bias(
    const float* __restrict__ a, const float* __restrict__ b,
    const float* __restrict__ c, float* __restrict__ o)
{
  const int i = blockIdx.x * 256 + threadIdx.x;   // 0..3071
  o[i] = i < DD ? a[i] : (i < 2 * DD ? b[i - DD] : c[i - 2 * DD]);
}

// ---------------- GEMM: C[M][N] = A[M][K] @ W[N][K]^T + bias(fp32), optional exact GELU
// m97 base + T3/T4-minimum: true LDS dbuf, counted vmcnt, raw s_barrier (no in-loop drain).
// BN=128 (4 n-frags/wave) or BN=64 (2 n-frags/wave, doubles grid for N=1024).
template<int GELU, int BN>
__global__ __launch_bounds__(256) void gemm_bt(
    const short* __restrict__ A, const short* __restrict__ W,
    const float* __restrict__ bias, short* __restrict__ C,
    int M, int N, int K)
{
  constexpr int NF = BN / 32;              // n-fragments per wave (col frags)
  __shared__ __align__(16) short As[2][128 * 32];
  __shared__ __align__(16) short Bs[2][BN * 32];
  const int t = threadIdx.x;
  const int lane = t & 63, wave = t >> 6;
  const int wr = wave >> 1, wc = wave & 1;
  const int l15 = lane & 15, lg = lane >> 4;
  const int bx = blockIdx.x, by = blockIdx.y;

  floatx4 zero = {0.f, 0.f, 0.f, 0.f};
  floatx4 acc[4][NF];
#pragma unroll
  for (int m = 0; m < 4; ++m)
#pragma unroll
    for (int n = 0; n < NF; ++n) acc[m][n] = zero;

  const size_t abase = (size_t)by * 128 * K;
  const size_t wbase = (size_t)bx * BN * K;

#define GSTAGE(bufi, kk) do {                                                 \
    _Pragma("unroll")                                                         \
    for (int i_ = 0; i_ < 2; ++i_) {                                          \
      const int slot = i_ * 256 + t, row_ = slot >> 2, cb_ = slot & 3;        \
      gload_lds16(A + abase + (size_t)row_ * K + (kk) + cb_ * 8,              \
                  &As[bufi][0] + (i_ * 256 + wave * 64) * 8);                 \
    }                                                                         \
    if constexpr (BN == 128) {                                                \
      _Pragma("unroll")                                                       \
      for (int i_ = 0; i_ < 2; ++i_) {                                        \
        const int slot = i_ * 256 + t, row_ = slot >> 2, cb_ = slot & 3;      \
        gload_lds16(W + wbase + (size_t)row_ * K + (kk) + cb_ * 8,            \
                    &Bs[bufi][0] + (i_ * 256 + wave * 64) * 8);               \
      }                                                                       \
    } else {                                                                  \
      const int row_ = t >> 2, cb_ = t & 3;                                   \
      gload_lds16(W + wbase + (size_t)row_ * K + (kk) + cb_ * 8,              \
                  &Bs[bufi][0] + wave * 512 + lane * 8);                      \
    }                                                                         \
  } while (0)

  GSTAGE(0, 0);
  int buf = 0;
  for (int k0 = 0; k0 < K; k0 += 32) {
    if (k0 + 32 < K) {
      GSTAGE(buf ^ 1, k0 + 32);
      if constexpr (BN == 128) asm volatile("s_waitcnt vmcnt(4)" ::: "memory");
      else                     asm volatile("s_waitcnt vmcnt(3)" ::: "memory");
    } else {
      asm volatile("s_waitcnt vmcnt(0)" ::: "memory");
    }
    __builtin_amdgcn_s_barrier();

    short8v af[4], bfr[NF];
#pragma unroll
    for (int m = 0; m < 4; ++m)
      af[m] = *(const short8v*)&As[buf][(wr * 64 + m * 16 + l15) * 32 + lg * 8];
#pragma unroll
    for (int n = 0; n < NF; ++n)
      bfr[n] = *(const short8v*)&Bs[buf][(wc * (BN / 2) + n * 16 + l15) * 32 + lg * 8];
#pragma unroll
    for (int m = 0; m < 4; ++m)
#pragma unroll
      for (int n = 0; n < NF; ++n)
        acc[m][n] = __builtin_amdgcn_mfma_f32_16x16x32_bf16(af[m], bfr[n], acc[m][n], 0, 0, 0);

    asm volatile("" ::: "memory");
    __builtin_amdgcn_s_barrier();
    buf ^= 1;
  }
#undef GSTAGE

#pragma unroll
  for (int n = 0; n < NF; ++n) {
    const int col = bx * BN + wc * (BN / 2) + n * 16 + l15;
    const float bv = bias[col];
#pragma unroll
    for (int m = 0; m < 4; ++m) {
      const int row0 = by * 128 + wr * 64 + m * 16 + lg * 4;
#pragma unroll
      for (int jj = 0; jj < 4; ++jj) {
        float v = acc[m][n][jj] + bv;
        if (GELU) v = 0.5f * v * (1.f + erff(v * 0.70710678118f));
        C[(size_t)(row0 + jj) * N + col] = f2bf(v);
      }
    }
  }
}

// ---------------- V transpose per (b,h): qkv[.][2048 + h*64 + dh] -> vt[B][H][64][T]
__global__ __launch_bounds__(256) void transpose_v(
    const short* __restrict__ qkv, short* __restrict__ vt)
{
  __shared__ short tile[64][65];
  const int tb = blockIdx.x, h = blockIdx.y, b = blockIdx.z;
  const int t = threadIdx.x;
  const int r = t >> 2, c4 = (t & 3) * 16;
  const short* src = qkv + ((size_t)(b * TT + tb * 64 + r)) * 3072 + 2048 + h * 64 + c4;
#pragma unroll
  for (int i = 0; i < 16; ++i) tile[r][c4 + i] = src[i];
  __syncthreads();
  short* dst = vt + ((size_t)((b * HH + h) * 64 + r)) * TT + tb * 64 + c4;
#pragma unroll
  for (int i = 0; i < 16; ++i) dst[i] = tile[c4 + i][r];
}

// ---------------- flash attention: 1 block = 128 q-rows of one (b,h); 4 waves,
// each wave: 2 q-sets of 16 rows. Swapped QK^T; counted-vmcnt dbuf; defer-max.
#define PSTR 72
__global__ __launch_bounds__(256) void flash_attn(
    const short* __restrict__ qkv, const short* __restrict__ vt,
    const int* __restrict__ mask, short* __restrict__ ctx)
{
  const int qb = blockIdx.x, h = blockIdx.y, b = blockIdx.z;
  const int t = threadIdx.x;
  const int lane = t & 63, wave = t >> 6;
  const int l15 = lane & 15, lg = lane >> 4;

  __shared__ __align__(16) short Ks[2][64 * 64];   // [key][dh], chunk-swizzled
  __shared__ __align__(16) short Vs[2][64 * 64];   // [dh][key], chunk-swizzled
  __shared__ __align__(16) short p_lds[4][16 * PSTR];
  short* prow = p_lds[wave];

  // Q fragments for 2 q-sets: rows qb*128 + set*64 + wave*16 + l15
  short8v qf0[2], qf1[2];
#pragma unroll
  for (int s_ = 0; s_ < 2; ++s_) {
    const short* qp = qkv + ((size_t)(b * TT + qb * 128 + s_ * 64 + wave * 16 + l15)) * 3072 + h * 64;
    qf0[s_] = *(const short8v*)(qp + lg * 8);
    qf1[s_] = *(const short8v*)(qp + 32 + lg * 8);
  }

  const short* kbase = qkv + (size_t)b * TT * 3072 + 1024 + h * 64; // + key*3072 + dh
  const short* vtb   = vt + ((size_t)(b * HH + h)) * 64 * TT;       // + dh*TT + key

  // staging geometry: 8 chunks/tile (1KB each), wave w stages chunks 2w, 2w+1
  const int srow = lane >> 3;                 // row within 8-row chunk
  const int scol = (lane & 7) ^ (srow & 7);   // pre-swizzled source 16B-chunk

  float m_run[2] = { -3e30f, -3e30f };
  float l_run[2] = { 0.f, 0.f };
  floatx4 zero = {0.f, 0.f, 0.f, 0.f};
  floatx4 o[2][4];
#pragma unroll
  for (int s_ = 0; s_ < 2; ++s_)
#pragma unroll
    for (int n = 0; n < 4; ++n) o[s_][n] = zero;

#define STAGE_KV(bufi, kb_) do {                                             \
    _Pragma("unroll")                                                        \
    for (int i_ = 0; i_ < 2; ++i_) {                                         \
      const int c_ = wave * 2 + i_;                                          \
      const int r_ = c_ * 8 + srow;                                          \
      gload_lds16(kbase + (size_t)((kb_) * 64 + r_) * 3072 + scol * 8,       \
                  &Ks[bufi][c_ * 512]);                                      \
      gload_lds16(vtb + (size_t)r_ * TT + (kb_) * 64 + scol * 8,             \
                  &Vs[bufi][c_ * 512]);                                      \
    }                                                                        \
  } while (0)

  STAGE_KV(0, 0);
  int buf = 0;
  for (int kb = 0; kb < NT; ++kb) {
    if (kb + 1 < NT) {
      STAGE_KV(buf ^ 1, kb + 1);                     // 4 loads in flight
      asm volatile("s_waitcnt vmcnt(4)" ::: "memory"); // wait current tile only
    } else {
      asm volatile("s_waitcnt vmcnt(0)" ::: "memory");
    }
    __builtin_amdgcn_s_barrier();

    // K/V fragments for this tile (shared by both q-sets)
    short8v kf0[4], kf1[4], vf0[4], vf1[4];
#pragma unroll
    for (int n = 0; n < 4; ++n) {
      const int row = n * 16 + l15;
      const int ch0 = lg ^ (row & 7);
      const int ch1 = (lg + 4) ^ (row & 7);
      kf0[n] = *(const short8v*)&Ks[buf][row * 64 + ch0 * 8];
      kf1[n] = *(const short8v*)&Ks[buf][row * 64 + ch1 * 8];
      vf0[n] = *(const short8v*)&Vs[buf][row * 64 + ch0 * 8];
      vf1[n] = *(const short8v*)&Vs[buf][row * 64 + ch1 * 8];
    }

    // mask multipliers for this tile: key = n*16 + lg*4 + jj
    float cm[4][4];
#pragma unroll
    for (int n = 0; n < 4; ++n) {
      const int4 mv = *(const int4*)&mask[b * TT + kb * 64 + n * 16 + lg * 4];
      cm[n][0] = mv.x ? 0.f : -1e30f; cm[n][1] = mv.y ? 0.f : -1e30f;
      cm[n][2] = mv.z ? 0.f : -1e30f; cm[n][3] = mv.w ? 0.f : -1e30f;
    }

#pragma unroll
    for (int s_ = 0; s_ < 2; ++s_) {
      // ---- S^T = K Q^T : lane holds q-row = l15, keys n*16 + lg*4 + jj
      floatx4 s[4];
#pragma unroll
      for (int n = 0; n < 4; ++n) {
        floatx4 a = zero;
        a = __builtin_amdgcn_mfma_f32_16x16x32_bf16(kf0[n], qf0[s_], a, 0, 0, 0);
        a = __builtin_amdgcn_mfma_f32_16x16x32_bf16(kf1[n], qf1[s_], a, 0, 0, 0);
        s[n] = a;
      }
#pragma unroll
      for (int n = 0; n < 4; ++n)
#pragma unroll
        for (int jj = 0; jj < 4; ++jj) s[n][jj] = fmaf(s[n][jj], 0.125f, cm[n][jj]);

      // ---- online softmax for q-row l15 (16 local keys + 2 shuffles)
      float mx = -3e30f;
#pragma unroll
      for (int n = 0; n < 4; ++n)
#pragma unroll
        for (int jj = 0; jj < 4; ++jj) mx = fmaxf(mx, s[n][jj]);
      mx = fmaxf(mx, __shfl_xor(mx, 16, 64));
      mx = fmaxf(mx, __shfl_xor(mx, 32, 64));

      // defer-max (T13): skip rescale when tile max grew <= 8 over running max
      const bool defer = __all(mx - m_run[s_] <= 8.f);
      const float mnew = defer ? m_run[s_] : fmaxf(m_run[s_], mx);
      float sum = 0.f;
#pragma unroll
      for (int n = 0; n < 4; ++n)
#pragma unroll
        for (int jj = 0; jj < 4; ++jj) {
          const float p = __expf(s[n][jj] - mnew);
          s[n][jj] = p;
          sum += p;
        }
      sum += __shfl_xor(sum, 16, 64);
      sum += __shfl_xor(sum, 32, 64);
      if (defer) {
        l_run[s_] += sum;
      } else {
        const float al = __expf(m_run[s_] - mnew);
        l_run[s_] = l_run[s_] * al + sum;
        m_run[s_] = mnew;
        float alo[4];
#pragma unroll
        for (int jj = 0; jj < 4; ++jj) alo[jj] = __shfl(al, lg * 4 + jj, 16);
#pragma unroll
        for (int n = 0; n < 4; ++n)
#pragma unroll
          for (int jj = 0; jj < 4; ++jj) o[s_][n][jj] *= alo[jj];
      }

      // ---- P -> LDS [q=l15][key], b64 writes; read back as A-frags (row=q)
#pragma unroll
      for (int n = 0; n < 4; ++n) {
        short4v pv;
#pragma unroll
        for (int jj = 0; jj < 4; ++jj) pv[jj] = f2bf(s[n][jj]);
        *(short4v*)&prow[l15 * PSTR + n * 16 + lg * 4] = pv;
      }
      const short8v pf0 = *(const short8v*)&prow[l15 * PSTR + lg * 8];
      const short8v pf1 = *(const short8v*)&prow[l15 * PSTR + 32 + lg * 8];

      // ---- O += P @ V
#pragma unroll
      for (int n = 0; n < 4; ++n) {
        o[s_][n] = __builtin_amdgcn_mfma_f32_16x16x32_bf16(pf0, vf0[n], o[s_][n], 0, 0, 0);
        o[s_][n] = __builtin_amdgcn_mfma_f32_16x16x32_bf16(pf1, vf1[n], o[s_][n], 0, 0, 0);
      }
    }
    asm volatile("" ::: "memory");
    __builtin_amdgcn_s_barrier();
    buf ^= 1;
  }
#undef STAGE_KV

#pragma unroll
  for (int s_ = 0; s_ < 2; ++s_)
#pragma unroll
    for (int jj = 0; jj < 4; ++jj) {
      const float inv = 1.f / __shfl(l_run[s_], lg * 4 + jj, 16);
      const int row = qb * 128 + s_ * 64 + wave * 16 + lg * 4 + jj;
#pragma unroll
      for (int n = 0; n < 4; ++n)
        ctx[((size_t)(b * TT + row)) * DD + h * 64 + n * 16 + l15] = f2bf(o[s_][n][jj] * inv);
    }
}

// ---------------- fused residual-add + LayerNorm; fp32 residual stream, fp32 g/b
__global__ __launch_bounds__(256) void add_ln(
    const float* __restrict__ xres, const short* __restrict__ add,
    const float* __restrict__ g, const float* __restrict__ bb,
    float* __restrict__ outf, short* __restrict__ outb)
{
  const int row = blockIdx.x, t = threadIdx.x;
  const int lane = t & 63, wave = t >> 6;
  const float4 xv = *(const float4*)(xres + (size_t)row * DD + t * 4);
  float y[4] = { xv.x, xv.y, xv.z, xv.w };
  if (add) {
    const short4v av = *(const short4v*)(add + (size_t)row * DD + t * 4);
#pragma unroll
    for (int i = 0; i < 4; ++i) y[i] += bf2f(av[i]);
  }
  float s = y[0] + y[1] + y[2] + y[3];
  float ss = y[0]*y[0] + y[1]*y[1] + y[2]*y[2] + y[3]*y[3];
#pragma unroll
  for (int off = 32; off >= 1; off >>= 1) {
    s  += __shfl_xor(s, off, 64);
    ss += __shfl_xor(ss, off, 64);
  }
  __shared__ float red[2][4];
  if (lane == 0) { red[0][wave] = s; red[1][wave] = ss; }
  __syncthreads();
  s  = red[0][0] + red[0][1] + red[0][2] + red[0][3];
  ss = red[1][0] + red[1][1] + red[1][2] + red[1][3];
  const float mu = s * (1.f / DD);
  const float var = ss * (1.f / DD) - mu * mu;
  const float rs = rsqrtf(var + 1e-5f);
  const float4 gv = *(const float4*)(g + t * 4);
  const float4 bv = *(const float4*)(bb + t * 4);
  float o[4];
  o[0] = (y[0] - mu) * rs * gv.x + bv.x;
  o[1] = (y[1] - mu) * rs * gv.y + bv.y;
  o[2] = (y[2] - mu) * rs * gv.z + bv.z;
  o[3] = (y[3] - mu) * rs * gv.w + bv.w;
  if (outf) *(float4*)(outf + (size_t)row * DD + t * 4) = make_float4(o[0], o[1], o[2], o[3]);
  if (outb) {
    short4v ov;
#pragma unroll
    for (int i = 0; i < 4; ++i) ov[i] = f2bf(o[i]);
    *(short4v*)(outb + (size_t)row * DD + t * 4) = ov;
  }
}

// ---------------- x (fp32) -> xf (fp32 copy) + xb (bf16)
__global__ __launch_bounds__(256) void cast_in(
    const float* __restrict__ x, float* __restrict__ xf,
    short* __restrict__ xb)
{
  const int i = (blockIdx.x * 256 + threadIdx.x) * 4;
  const float4 v = *(const float4*)(x + i);
  *(float4*)(xf + i) = v;
  short4v o; o[0] = f2bf(v.x); o[1] = f2bf(v.y); o[2] = f2bf(v.z); o[3] = f2bf(v.w);
  *(short4v*)(xb + i) = o;
}

extern "C" void kernel_launch(void* const* d_in, const int* in_sizes, int n_in,
                              void* d_out, int out_size, void* d_ws, size_t ws_size,
                              hipStream_t stream) {
  const float* x   = (const float*)d_in[0];
  const int* mask  = (const int*)d_in[1];
  const float* Wq  = (const float*)d_in[2];
  const float* bq  = (const float*)d_in[3];
  const float* Wk  = (const float*)d_in[4];
  const float* bk  = (const float*)d_in[5];
  const float* Wv  = (const float*)d_in[6];
  const float* bv  = (const float*)d_in[7];
  const float* Wo  = (const float*)d_in[8];
  const float* bo  = (const float*)d_in[9];
  const float* f1w = (const float*)d_in[10];
  const float* f1b = (const float*)d_in[11];
  const float* f2w = (const float*)d_in[12];
  const float* f2b = (const float*)d_in[13];
  const float* l1g = (const float*)d_in[14];
  const float* l1b = (const float*)d_in[15];
  const float* l2g = (const float*)d_in[16];
  const float* l2b = (const float*)d_in[17];
  const float* lfg = (const float*)d_in[18];
  const float* lfb = (const float*)d_in[19];
  float* out = (float*)d_out;   // reference output dtype is float32

  char* ws = (char*)d_ws;
  const size_t MB = 1u << 20;
  float* xf   = (float*)(ws);              // 16 MB fp32 residual stream
  short* xb   = (short*)(ws + 16 * MB);    // 8 MB bf16 x
  short* qkv  = (short*)(ws + 24 * MB);    // 24 MB fused QKV [4096][3072]
  short* vt_  = (short*)(ws + 48 * MB);    // 8 MB V^T [B][H][64][T]
  short* ctx  = (short*)(ws + 56 * MB);    // 8 MB
  short* tmp  = (short*)(ws + 64 * MB);    // 8 MB attn_out / ff_out
  float* fbias= (float*)(ws + 64 * MB);    // 12 KB fused QKV bias (aliases tmp; dead by Wo GEMM)
  short* wbuf = (short*)(ws + 72 * MB);    // 24 MB layer weights (bf16)
  short* hb   = qkv;                       // 32 MB FFN hidden, aliases dead qkv/vt

  cast_in<<<(MM * DD) / (256 * 4), 256, 0, stream>>>(x, xf, xb);

  for (int l = 0; l < LL; ++l) {
    cast_layer<<<WTOT / (256 * 4), 256, 0, stream>>>(
        Wq + (size_t)l * SEG, Wk + (size_t)l * SEG, Wv + (size_t)l * SEG, Wo + (size_t)l * SEG,
        f1w + (size_t)l * DFF * DD, f2w + (size_t)l * DD * DFF, wbuf);
    concat_bias<<<12, 256, 0, stream>>>(bq + l * DD, bk + l * DD, bv + l * DD, fbias);
    const short* wqkv_b = wbuf;                       // [3072][1024]
    const short* wo_b   = wbuf + 3 * SEG;
    const short* f1_b   = wbuf + 4 * SEG;
    const short* f2_b   = wbuf + 4 * SEG + DFF * DD;

    gemm_bt<0,128><<<dim3(3072 / 128, MM / 128), 256, 0, stream>>>(xb, wqkv_b, fbias, qkv, MM, 3072, DD);
    transpose_v<<<dim3(TT / 64, HH, BB), 256, 0, stream>>>(qkv, vt_);
    flash_attn<<<dim3(TT / 128, HH, BB), 256, 0, stream>>>(qkv, vt_, mask, ctx);
    gemm_bt<0,64><<<dim3(DD / 64, MM / 128), 256, 0, stream>>>(ctx, wo_b, bo + l * DD, tmp, MM, DD, DD);
    add_ln<<<MM, 256, 0, stream>>>(xf, tmp, l1g + l * DD, l1b + l * DD, xf, xb);
    gemm_bt<1,128><<<dim3(DFF / 128, MM / 128), 256, 0, stream>>>(xb, f1_b, f1b + l * DFF, hb, MM, DFF, DD);
    gemm_bt<0,64><<<dim3(DD / 64, MM / 128), 256, 0, stream>>>(hb, f2_b, f2b + l * DD, tmp, MM, DD, DFF);
    add_ln<<<MM, 256, 0, stream>>>(xf, tmp, l2g + l * DD, l2b + l * DD, xf, xb);
  }
  add_ln<<<MM, 256, 0, stream>>>(xf, nullptr, lfg, lfb, out, nullptr);
}

// Round 7
// 1223.361 us; speedup vs baseline: 1.7433x; 1.0191x over previous
//
#include <hip/hip_runtime.h>
#include <hip/hip_bf16.h>
#include <cstdint>

#define BB 2
#define TT 2048
#define DD 1024
#define HH 16
#define DHH 64
#define DFF 4096
#define LL 4
#define MM (BB*TT)   // 4096 rows
#define NT (TT/64)   // 32 key tiles

typedef __attribute__((ext_vector_type(8))) short short8v;
typedef __attribute__((ext_vector_type(4))) short short4v;
typedef __attribute__((ext_vector_type(4))) float floatx4;

typedef __attribute__((address_space(3))) void lds_void;
typedef const __attribute__((address_space(1))) void glb_void;

__device__ __forceinline__ void gload_lds16(const void* g, void* l) {
  __builtin_amdgcn_global_load_lds((glb_void*)g, (lds_void*)l, 16, 0, 0);
}

__device__ __forceinline__ float bf2f(short s) {
  union { unsigned u; float f; } v; v.u = ((unsigned)(unsigned short)s) << 16; return v.f;
}
__device__ __forceinline__ short f2bf(float f) {
  union { float f; unsigned u; } v; v.f = f;
  unsigned r = (v.u + 0x7fffu + ((v.u >> 16) & 1u)) >> 16;
  return (short)r;
}
__device__ __forceinline__ unsigned pack2bf(float a, float b) {
  __hip_bfloat162 h = __float22bfloat162_rn(make_float2(a, b));
  return *reinterpret_cast<unsigned*>(&h);
}

// ---------------- fp32 -> bf16 cast of one layer's 6 weight matrices into one buffer
#define SEG (DD*DD)              // 1048576
#define WTOT (4*SEG + 2*DFF*DD)  // 12582912
__global__ __launch_bounds__(256) void cast_layer(
    const float* __restrict__ wq, const float* __restrict__ wk,
    const float* __restrict__ wv, const float* __restrict__ wo,
    const float* __restrict__ f1, const float* __restrict__ f2,
    short* __restrict__ dst)
{
  const int i = (blockIdx.x * 256 + threadIdx.x) * 4;
  const float* src; int off;
  if      (i <     SEG) { src = wq; off = i; }
  else if (i < 2 * SEG) { src = wk; off = i - SEG; }
  else if (i < 3 * SEG) { src = wv; off = i - 2 * SEG; }
  else if (i < 4 * SEG) { src = wo; off = i - 3 * SEG; }
  else if (i < 4 * SEG + DFF * DD) { src = f1; off = i - 4 * SEG; }
  else { src = f2; off = i - 4 * SEG - DFF * DD; }
  const float4 v = *(const float4*)(src + off);
  short4v o; o[0] = f2bf(v.x); o[1] = f2bf(v.y); o[2] = f2bf(v.z); o[3] = f2bf(v.w);
  *(short4v*)(dst + i) = o;
}

__global__ __launch_bounds__(256) void concat_bias(
    const float* __restrict__ a, const float* __restrict__ b,
    const float* __restrict__ c, float* __restrict__ o)
{
  const int i = blockIdx.x * 256 + threadIdx.x;   // 0..3071
  o[i] = i < DD ? a[i] : (i < 2 * DD ? b[i - DD] : c[i - 2 * DD]);
}

// ---------------- GEMM: C[M][N] = A[M][K] @ W[N][K]^T + bias(fp32), optional exact GELU
// m97 base + counted-vmcnt dbuf + XCD-chunked block swizzle (T1).
template<int GELU, int BN>
__global__ __launch_bounds__(256) void gemm_bt(
    const short* __restrict__ A, const short* __restrict__ W,
    const float* __restrict__ bias, short* __restrict__ C,
    int M, int N, int K)
{
  constexpr int NF = BN / 32;              // n-fragments per wave
  __shared__ __align__(16) short As[2][128 * 32];
  __shared__ __align__(16) short Bs[2][BN * 32];
  const int t = threadIdx.x;
  const int lane = t & 63, wave = t >> 6;
  const int wr = wave >> 1, wc = wave & 1;
  const int l15 = lane & 15, lg = lane >> 4;

  // XCD-chunked swizzle: all grids are multiples of 8
  const int nwg = gridDim.x * gridDim.y;
  const int bid0 = blockIdx.y * gridDim.x + blockIdx.x;
  const int q8 = nwg >> 3;
  const int lid = (bid0 & 7) * q8 + (bid0 >> 3);
  const int bx = lid % gridDim.x, by = lid / gridDim.x;

  floatx4 zero = {0.f, 0.f, 0.f, 0.f};
  floatx4 acc[4][NF];
#pragma unroll
  for (int m = 0; m < 4; ++m)
#pragma unroll
    for (int n = 0; n < NF; ++n) acc[m][n] = zero;

  const size_t abase = (size_t)by * 128 * K;
  const size_t wbase = (size_t)bx * BN * K;

#define GSTAGE(bufi, kk) do {                                                 \
    _Pragma("unroll")                                                         \
    for (int i_ = 0; i_ < 2; ++i_) {                                          \
      const int slot = i_ * 256 + t, row_ = slot >> 2, cb_ = slot & 3;        \
      gload_lds16(A + abase + (size_t)row_ * K + (kk) + cb_ * 8,              \
                  &As[bufi][0] + (i_ * 256 + wave * 64) * 8);                 \
    }                                                                         \
    if constexpr (BN == 128) {                                                \
      _Pragma("unroll")                                                       \
      for (int i_ = 0; i_ < 2; ++i_) {                                        \
        const int slot = i_ * 256 + t, row_ = slot >> 2, cb_ = slot & 3;      \
        gload_lds16(W + wbase + (size_t)row_ * K + (kk) + cb_ * 8,            \
                    &Bs[bufi][0] + (i_ * 256 + wave * 64) * 8);               \
      }                                                                       \
    } else {                                                                  \
      const int row_ = t >> 2, cb_ = t & 3;                                   \
      gload_lds16(W + wbase + (size_t)row_ * K + (kk) + cb_ * 8,              \
                  &Bs[bufi][0] + wave * 512 + lane * 8);                      \
    }                                                                         \
  } while (0)

  GSTAGE(0, 0);
  int buf = 0;
  for (int k0 = 0; k0 < K; k0 += 32) {
    if (k0 + 32 < K) {
      GSTAGE(buf ^ 1, k0 + 32);
      if constexpr (BN == 128) asm volatile("s_waitcnt vmcnt(4)" ::: "memory");
      else                     asm volatile("s_waitcnt vmcnt(3)" ::: "memory");
    } else {
      asm volatile("s_waitcnt vmcnt(0)" ::: "memory");
    }
    __builtin_amdgcn_s_barrier();

    short8v af[4], bfr[NF];
#pragma unroll
    for (int m = 0; m < 4; ++m)
      af[m] = *(const short8v*)&As[buf][(wr * 64 + m * 16 + l15) * 32 + lg * 8];
#pragma unroll
    for (int n = 0; n < NF; ++n)
      bfr[n] = *(const short8v*)&Bs[buf][(wc * (BN / 2) + n * 16 + l15) * 32 + lg * 8];
#pragma unroll
    for (int m = 0; m < 4; ++m)
#pragma unroll
      for (int n = 0; n < NF; ++n)
        acc[m][n] = __builtin_amdgcn_mfma_f32_16x16x32_bf16(af[m], bfr[n], acc[m][n], 0, 0, 0);

    asm volatile("" ::: "memory");
    __builtin_amdgcn_s_barrier();
    buf ^= 1;
  }
#undef GSTAGE

#pragma unroll
  for (int n = 0; n < NF; ++n) {
    const int col = bx * BN + wc * (BN / 2) + n * 16 + l15;
    const float bv = bias[col];
#pragma unroll
    for (int m = 0; m < 4; ++m) {
      const int row0 = by * 128 + wr * 64 + m * 16 + lg * 4;
#pragma unroll
      for (int jj = 0; jj < 4; ++jj) {
        float v = acc[m][n][jj] + bv;
        if (GELU) v = 0.5f * v * (1.f + erff(v * 0.70710678118f));
        C[(size_t)(row0 + jj) * N + col] = f2bf(v);
      }
    }
  }
}

// ---------------- V transpose per (b,h): qkv[.][2048 + h*64 + dh] -> vt[B][H][64][T]
__global__ __launch_bounds__(256) void transpose_v(
    const short* __restrict__ qkv, short* __restrict__ vt)
{
  __shared__ short tile[64][65];
  const int tb = blockIdx.x, h = blockIdx.y, b = blockIdx.z;
  const int t = threadIdx.x;
  const int r = t >> 2, c4 = (t & 3) * 16;
  const short* src = qkv + ((size_t)(b * TT + tb * 64 + r)) * 3072 + 2048 + h * 64 + c4;
#pragma unroll
  for (int i = 0; i < 16; ++i) tile[r][c4 + i] = src[i];
  __syncthreads();
  short* dst = vt + ((size_t)((b * HH + h) * 64 + r)) * TT + tb * 64 + c4;
#pragma unroll
  for (int i = 0; i < 16; ++i) dst[i] = tile[c4 + i][r];
}

// ---------------- flash attention: 1 block = 128 q-rows; 8 waves x 16 q-rows.
// Swapped QK^T, exp2-domain softmax, counted-vmcnt dbuf, defer-max, XCD swizzle.
#define PSTR 72
#define SCL2 0.18033688011112042f   // 0.125 * log2(e)
__global__ __launch_bounds__(512, 4) void flash_attn(
    const short* __restrict__ qkv, const short* __restrict__ vt,
    const int* __restrict__ mask, short* __restrict__ ctx)
{
  const int t = threadIdx.x;
  const int lane = t & 63, wave = t >> 6;   // wave 0..7
  const int l15 = lane & 15, lg = lane >> 4;

  // XCD-chunked swizzle over the 512-block grid
  const int bid0 = blockIdx.x + gridDim.x * (blockIdx.y + gridDim.y * blockIdx.z);
  const int lid = (bid0 & 7) * 64 + (bid0 >> 3);
  const int qb = lid & 15, h = (lid >> 4) & 15, b = lid >> 8;

  __shared__ __align__(16) short Ks[2][64 * 64];   // [key][dh], chunk-swizzled
  __shared__ __align__(16) short Vs[2][64 * 64];   // [dh][key], chunk-swizzled
  __shared__ __align__(16) short p_lds[8][16 * PSTR];
  short* prow = p_lds[wave];

  // Q fragments: rows qb*128 + wave*16 + l15
  const short* qp = qkv + ((size_t)(b * TT + qb * 128 + wave * 16 + l15)) * 3072 + h * 64;
  const short8v qf0 = *(const short8v*)(qp + lg * 8);
  const short8v qf1 = *(const short8v*)(qp + 32 + lg * 8);

  const short* kbase = qkv + (size_t)b * TT * 3072 + 1024 + h * 64; // + key*3072 + dh
  const short* vtb   = vt + ((size_t)(b * HH + h)) * 64 * TT;       // + dh*TT + key

  // staging: 8 chunks (8 rows x 64 cols each); wave w stages chunk w of K and V
  const int srow = lane >> 3;                 // row within chunk
  const int scol = (lane & 7) ^ (srow & 7);   // pre-swizzled source 16B-chunk

  float m_run = -3e30f, l_run = 0.f;
  floatx4 zero = {0.f, 0.f, 0.f, 0.f};
  floatx4 o[4];
#pragma unroll
  for (int n = 0; n < 4; ++n) o[n] = zero;

#define STAGE_KV(bufi, kb_) do {                                             \
    const int r_ = wave * 8 + srow;                                          \
    gload_lds16(kbase + (size_t)((kb_) * 64 + r_) * 3072 + scol * 8,         \
                &Ks[bufi][wave * 512]);                                      \
    gload_lds16(vtb + (size_t)r_ * TT + (kb_) * 64 + scol * 8,               \
                &Vs[bufi][wave * 512]);                                      \
  } while (0)

  STAGE_KV(0, 0);
  int buf = 0;
  for (int kb = 0; kb < NT; ++kb) {
    if (kb + 1 < NT) {
      STAGE_KV(buf ^ 1, kb + 1);                       // 2 next-tile loads in flight
      asm volatile("s_waitcnt vmcnt(2)" ::: "memory"); // wait current tile only
    } else {
      asm volatile("s_waitcnt vmcnt(0)" ::: "memory");
    }
    __builtin_amdgcn_s_barrier();

    // mask multipliers (log2 domain): key = n*16 + lg*4 + jj
    float cm[4][4];
#pragma unroll
    for (int n = 0; n < 4; ++n) {
      const int4 mv = *(const int4*)&mask[b * TT + kb * 64 + n * 16 + lg * 4];
      cm[n][0] = mv.x ? 0.f : -1.5e30f; cm[n][1] = mv.y ? 0.f : -1.5e30f;
      cm[n][2] = mv.z ? 0.f : -1.5e30f; cm[n][3] = mv.w ? 0.f : -1.5e30f;
    }

    // ---- S^T = K Q^T : lane holds q-row = l15, keys n*16 + lg*4 + jj
    floatx4 s[4];
#pragma unroll
    for (int n = 0; n < 4; ++n) {
      const int row = n * 16 + l15;
      const int ch0 = lg ^ (row & 7);
      const int ch1 = (lg + 4) ^ (row & 7);
      const short8v kf0 = *(const short8v*)&Ks[buf][row * 64 + ch0 * 8];
      const short8v kf1 = *(const short8v*)&Ks[buf][row * 64 + ch1 * 8];
      floatx4 a = zero;
      a = __builtin_amdgcn_mfma_f32_16x16x32_bf16(kf0, qf0, a, 0, 0, 0);
      a = __builtin_amdgcn_mfma_f32_16x16x32_bf16(kf1, qf1, a, 0, 0, 0);
      s[n] = a;
    }
#pragma unroll
    for (int n = 0; n < 4; ++n)
#pragma unroll
      for (int jj = 0; jj < 4; ++jj) s[n][jj] = fmaf(s[n][jj], SCL2, cm[n][jj]);

    // ---- online softmax (log2 domain) for q-row l15
    float mx = -3e30f;
#pragma unroll
    for (int n = 0; n < 4; ++n)
#pragma unroll
      for (int jj = 0; jj < 4; ++jj) mx = fmaxf(mx, s[n][jj]);
    mx = fmaxf(mx, __shfl_xor(mx, 16, 64));
    mx = fmaxf(mx, __shfl_xor(mx, 32, 64));

    const bool defer = __all(mx - m_run <= 11.5f);   // ~e^8 bound on P
    const float mnew = defer ? m_run : fmaxf(m_run, mx);
    float sum = 0.f;
#pragma unroll
    for (int n = 0; n < 4; ++n)
#pragma unroll
      for (int jj = 0; jj < 4; ++jj) {
        const float p = exp2f(s[n][jj] - mnew);
        s[n][jj] = p;
        sum += p;
      }
    sum += __shfl_xor(sum, 16, 64);
    sum += __shfl_xor(sum, 32, 64);
    if (defer) {
      l_run += sum;
    } else {
      const float al = exp2f(m_run - mnew);
      l_run = l_run * al + sum;
      m_run = mnew;
      float alo[4];
#pragma unroll
      for (int jj = 0; jj < 4; ++jj) alo[jj] = __shfl(al, lg * 4 + jj, 16);
#pragma unroll
      for (int n = 0; n < 4; ++n)
#pragma unroll
        for (int jj = 0; jj < 4; ++jj) o[n][jj] *= alo[jj];
    }

    // ---- P -> LDS [q=l15][key] via packed bf16 cvt; read back as A-frags (row=q)
#pragma unroll
    for (int n = 0; n < 4; ++n) {
      const unsigned u0 = pack2bf(s[n][0], s[n][1]);
      const unsigned u1 = pack2bf(s[n][2], s[n][3]);
      *(uint2*)&prow[l15 * PSTR + n * 16 + lg * 4] = make_uint2(u0, u1);
    }
    const short8v pf0 = *(const short8v*)&prow[l15 * PSTR + lg * 8];
    const short8v pf1 = *(const short8v*)&prow[l15 * PSTR + 32 + lg * 8];

    // ---- O += P @ V
#pragma unroll
    for (int n = 0; n < 4; ++n) {
      const int row = n * 16 + l15;
      const int ch0 = lg ^ (row & 7);
      const int ch1 = (lg + 4) ^ (row & 7);
      const short8v vf0 = *(const short8v*)&Vs[buf][row * 64 + ch0 * 8];
      const short8v vf1 = *(const short8v*)&Vs[buf][row * 64 + ch1 * 8];
      o[n] = __builtin_amdgcn_mfma_f32_16x16x32_bf16(pf0, vf0, o[n], 0, 0, 0);
      o[n] = __builtin_amdgcn_mfma_f32_16x16x32_bf16(pf1, vf1, o[n], 0, 0, 0);
    }
    asm volatile("" ::: "memory");
    __builtin_amdgcn_s_barrier();
    buf ^= 1;
  }
#undef STAGE_KV

#pragma unroll
  for (int jj = 0; jj < 4; ++jj) {
    const float inv = 1.f / __shfl(l_run, lg * 4 + jj, 16);
    const int row = qb * 128 + wave * 16 + lg * 4 + jj;
#pragma unroll
    for (int n = 0; n < 4; ++n)
      ctx[((size_t)(b * TT + row)) * DD + h * 64 + n * 16 + l15] = f2bf(o[n][jj] * inv);
  }
}

// ---------------- fused residual-add + LayerNorm; fp32 residual stream, fp32 g/b
__global__ __launch_bounds__(256) void add_ln(
    const float* __restrict__ xres, const short* __restrict__ add,
    const float* __restrict__ g, const float* __restrict__ bb,
    float* __restrict__ outf, short* __restrict__ outb)
{
  const int row = blockIdx.x, t = threadIdx.x;
  const int lane = t & 63, wave = t >> 6;
  const float4 xv = *(const float4*)(xres + (size_t)row * DD + t * 4);
  float y[4] = { xv.x, xv.y, xv.z, xv.w };
  if (add) {
    const short4v av = *(const short4v*)(add + (size_t)row * DD + t * 4);
#pragma unroll
    for (int i = 0; i < 4; ++i) y[i] += bf2f(av[i]);
  }
  float s = y[0] + y[1] + y[2] + y[3];
  float ss = y[0]*y[0] + y[1]*y[1] + y[2]*y[2] + y[3]*y[3];
#pragma unroll
  for (int off = 32; off >= 1; off >>= 1) {
    s  += __shfl_xor(s, off, 64);
    ss += __shfl_xor(ss, off, 64);
  }
  __shared__ float red[2][4];
  if (lane == 0) { red[0][wave] = s; red[1][wave] = ss; }
  __syncthreads();
  s  = red[0][0] + red[0][1] + red[0][2] + red[0][3];
  ss = red[1][0] + red[1][1] + red[1][2] + red[1][3];
  const float mu = s * (1.f / DD);
  const float var = ss * (1.f / DD) - mu * mu;
  const float rs = rsqrtf(var + 1e-5f);
  const float4 gv = *(const float4*)(g + t * 4);
  const float4 bv = *(const float4*)(bb + t * 4);
  float o[4];
  o[0] = (y[0] - mu) * rs * gv.x + bv.x;
  o[1] = (y[1] - mu) * rs * gv.y + bv.y;
  o[2] = (y[2] - mu) * rs * gv.z + bv.z;
  o[3] = (y[3] - mu) * rs * gv.w + bv.w;
  if (outf) *(float4*)(outf + (size_t)row * DD + t * 4) = make_float4(o[0], o[1], o[2], o[3]);
  if (outb) {
    short4v ov;
#pragma unroll
    for (int i = 0; i < 4; ++i) ov[i] = f2bf(o[i]);
    *(short4v*)(outb + (size_t)row * DD + t * 4) = ov;
  }
}

// ---------------- x (fp32) -> xf (fp32 copy) + xb (bf16)
__global__ __launch_bounds__(256) void cast_in(
    const float* __restrict__ x, float* __restrict__ xf,
    short* __restrict__ xb)
{
  const int i = (blockIdx.x * 256 + threadIdx.x) * 4;
  const float4 v = *(const float4*)(x + i);
  *(float4*)(xf + i) = v;
  short4v o; o[0] = f2bf(v.x); o[1] = f2bf(v.y); o[2] = f2bf(v.z); o[3] = f2bf(v.w);
  *(short4v*)(xb + i) = o;
}

extern "C" void kernel_launch(void* const* d_in, const int* in_sizes, int n_in,
                              void* d_out, int out_size, void* d_ws, size_t ws_size,
                              hipStream_t stream) {
  const float* x   = (const float*)d_in[0];
  const int* mask  = (const int*)d_in[1];
  const float* Wq  = (const float*)d_in[2];
  const float* bq  = (const float*)d_in[3];
  const float* Wk  = (const float*)d_in[4];
  const float* bk  = (const float*)d_in[5];
  const float* Wv  = (const float*)d_in[6];
  const float* bv  = (const float*)d_in[7];
  const float* Wo  = (const float*)d_in[8];
  const float* bo  = (const float*)d_in[9];
  const float* f1w = (const float*)d_in[10];
  const float* f1b = (const float*)d_in[11];
  const float* f2w = (const float*)d_in[12];
  const float* f2b = (const float*)d_in[13];
  const float* l1g = (const float*)d_in[14];
  const float* l1b = (const float*)d_in[15];
  const float* l2g = (const float*)d_in[16];
  const float* l2b = (const float*)d_in[17];
  const float* lfg = (const float*)d_in[18];
  const float* lfb = (const float*)d_in[19];
  float* out = (float*)d_out;   // reference output dtype is float32

  char* ws = (char*)d_ws;
  const size_t MB = 1u << 20;
  float* xf   = (float*)(ws);              // 16 MB fp32 residual stream
  short* xb   = (short*)(ws + 16 * MB);    // 8 MB bf16 x
  short* qkv  = (short*)(ws + 24 * MB);    // 24 MB fused QKV [4096][3072]
  short* vt_  = (short*)(ws + 48 * MB);    // 8 MB V^T [B][H][64][T]
  short* ctx  = (short*)(ws + 56 * MB);    // 8 MB
  short* tmp  = (short*)(ws + 64 * MB);    // 8 MB attn_out / ff_out
  float* fbias= (float*)(ws + 64 * MB);    // 12 KB fused QKV bias (aliases tmp; dead by Wo GEMM)
  short* wbuf = (short*)(ws + 72 * MB);    // 24 MB layer weights (bf16)
  short* hb   = qkv;                       // 32 MB FFN hidden, aliases dead qkv/vt

  cast_in<<<(MM * DD) / (256 * 4), 256, 0, stream>>>(x, xf, xb);

  for (int l = 0; l < LL; ++l) {
    cast_layer<<<WTOT / (256 * 4), 256, 0, stream>>>(
        Wq + (size_t)l * SEG, Wk + (size_t)l * SEG, Wv + (size_t)l * SEG, Wo + (size_t)l * SEG,
        f1w + (size_t)l * DFF * DD, f2w + (size_t)l * DD * DFF, wbuf);
    concat_bias<<<12, 256, 0, stream>>>(bq + l * DD, bk + l * DD, bv + l * DD, fbias);
    const short* wqkv_b = wbuf;                       // [3072][1024]
    const short* wo_b   = wbuf + 3 * SEG;
    const short* f1_b   = wbuf + 4 * SEG;
    const short* f2_b   = wbuf + 4 * SEG + DFF * DD;

    gemm_bt<0,128><<<dim3(3072 / 128, MM / 128), 256, 0, stream>>>(xb, wqkv_b, fbias, qkv, MM, 3072, DD);
    transpose_v<<<dim3(TT / 64, HH, BB), 256, 0, stream>>>(qkv, vt_);
    flash_attn<<<dim3(TT / 128, HH, BB), 512, 0, stream>>>(qkv, vt_, mask, ctx);
    gemm_bt<0,64><<<dim3(DD / 64, MM / 128), 256, 0, stream>>>(ctx, wo_b, bo + l * DD, tmp, MM, DD, DD);
    add_ln<<<MM, 256, 0, stream>>>(xf, tmp, l1g + l * DD, l1b + l * DD, xf, xb);
    gemm_bt<1,128><<<dim3(DFF / 128, MM / 128), 256, 0, stream>>>(xb, f1_b, f1b + l * DFF, hb, MM, DFF, DD);
    gemm_bt<0,64><<<dim3(DD / 64, MM / 128), 256, 0, stream>>>(hb, f2_b, f2b + l * DD, tmp, MM, DD, DFF);
    add_ln<<<MM, 256, 0, stream>>>(xf, tmp, l2g + l * DD, l2b + l * DD, xf, xb);
  }
  add_ln<<<MM, 256, 0, stream>>>(xf, nullptr, lfg, lfb, out, nullptr);
}